// Round 2
// 87.360 us; speedup vs baseline: 1.0532x; 1.0532x over previous
//
#include <hip/hip_runtime.h>
#include <math.h>

#ifndef M_PI
#define M_PI 3.14159265358979323846
#endif

constexpr int N    = 1024;
constexpr int M    = 4096;
constexpr int RANK = 32;
constexpr float PHI1 = -1.5339807878856412e-3f;   // -2*pi/4096

typedef __attribute__((ext_vector_type(8))) short bf16x8;
typedef __attribute__((ext_vector_type(4))) float f32x4;

__device__ __forceinline__ float softplus_f(float x) {
    return (x > 0.0f) ? (x + log1pf(__expf(-x))) : log1pf(__expf(x));
}

__device__ __forceinline__ short bf16_rne(float x) {
    unsigned u = __float_as_uint(x);
    u = (u + 0x7fffu + ((u >> 16) & 1u)) >> 16;
    return (short)u;
}

__device__ __forceinline__ unsigned pack_bf16x2(float a, float b) {
    return (unsigned)(unsigned short)bf16_rne(a)
         | ((unsigned)(unsigned short)bf16_rne(b) << 16);
}

// ===========================================================================
// DFT stage 1: G[d][r][k0] = sum_k1 sp(h[d][64k1+k0]) e^{-2pi i k1 r/64}
// grid (8 rG, 32 d), block 256.  (validated R10-R17, unchanged)
// ===========================================================================
__global__ __launch_bounds__(256) void dft_s1(const float* __restrict__ H,
                                              float* __restrict__ GR,
                                              float* __restrict__ GI) {
    __shared__ float sh[M];              // 16 KB
    const int d = blockIdx.y, tid = threadIdx.x;
    const float4* H4 = (const float4*)(H + d * M);
    for (int i = tid; i < M / 4; i += 256) {
        const float4 v = H4[i];
        ((float4*)sh)[i] = make_float4(softplus_f(v.x), softplus_f(v.y),
                                       softplus_f(v.z), softplus_f(v.w));
    }
    __syncthreads();

    const int k0 = tid & 63;
    const int r0 = blockIdx.x * 8 + (tid >> 6) * 2;
    float twR0 = 1.f, twI0 = 0.f, aR0 = 0.f, aI0 = 0.f;
    float twR1 = 1.f, twI1 = 0.f, aR1 = 0.f, aI1 = 0.f;
    float s0, c0, s1, c1;
    __sincosf((-2.0f * (float)M_PI / 64.0f) * (float)r0,       &s0, &c0);
    __sincosf((-2.0f * (float)M_PI / 64.0f) * (float)(r0 + 1), &s1, &c1);

    for (int k1 = 0; k1 < 64; ++k1) {
        const float h = sh[(k1 << 6) + k0];
        aR0 = fmaf(h, twR0, aR0);  aI0 = fmaf(h, twI0, aI0);
        aR1 = fmaf(h, twR1, aR1);  aI1 = fmaf(h, twI1, aI1);
        float nR = fmaf(twR0, c0, -twI0 * s0);
        float nI = fmaf(twR0, s0,  twI0 * c0);
        twR0 = nR; twI0 = nI;
        nR = fmaf(twR1, c1, -twI1 * s1);
        nI = fmaf(twR1, s1,  twI1 * c1);
        twR1 = nR; twI1 = nI;
    }
    const int base = d * 4096 + r0 * 64 + k0;
    GR[base]      = aR0;  GI[base]      = aI0;
    GR[base + 64] = aR1;  GI[base + 64] = aI1;
}

// ===========================================================================
// DFT stage 2: Hf[d][m] = sum_k0 G[d][m&63][k0] e^{-2pi i k0 m/4096}
// grid (16 mG, 32 d), block 256.  (validated R10-R17, unchanged)
// ===========================================================================
__global__ __launch_bounds__(256) void dft_s2(const float* __restrict__ GR,
                                              const float* __restrict__ GI,
                                              float* __restrict__ HfR,
                                              float* __restrict__ HfI) {
    __shared__ float sGR[64 * 65], sGI[64 * 65];   // 33.3 KB
    const int d = blockIdx.y, tid = threadIdx.x;
    const float4* gr4 = (const float4*)(GR + d * 4096);
    const float4* gi4 = (const float4*)(GI + d * 4096);
    for (int i4 = tid; i4 < 1024; i4 += 256) {
        const int r = i4 >> 4, k0 = (i4 & 15) << 2;
        const float4 vr = gr4[i4];
        const float4 vi = gi4[i4];
        const int p = r * 65 + k0;
        sGR[p] = vr.x; sGR[p+1] = vr.y; sGR[p+2] = vr.z; sGR[p+3] = vr.w;
        sGI[p] = vi.x; sGI[p+1] = vi.y; sGI[p+2] = vi.z; sGI[p+3] = vi.w;
    }
    __syncthreads();

    const int m = blockIdx.x * 256 + tid;
    const int rb = (m & 63) * 65;
    float ss, sc; __sincosf(PHI1 * (float)m, &ss, &sc);
    float tR_ = 1.f, tI_ = 0.f, accR = 0.f, accI = 0.f;
    #pragma unroll 8
    for (int k0 = 0; k0 < 64; ++k0) {
        const float gr = sGR[rb + k0], gi = sGI[rb + k0];
        accR = fmaf(tR_, gr, fmaf(-tI_, gi, accR));
        accI = fmaf(tR_, gi, fmaf( tI_, gr, accI));
        const float nR = fmaf(tR_, sc, -tI_ * ss);
        const float nI = fmaf(tR_, ss,  tI_ * sc);
        tR_ = nR; tI_ = nI;
    }
    HfR[d * M + m] = accR;
    HfI[d * M + m] = accI;
}

// ===========================================================================
// MFMA einsum — R18 (resubmit; prior round failed on container acquisition).
// Cooperative bf16 B-plane conversion at staging: the 6 B operands
// (hr, hi, hr*dlt, hi*dlt, hr*d2, hi*d2) depend only on (m,d) — previously
// each of the 4 waves recomputed all 48 converts per mt (~1500 VALU
// insts/thread). Now converted ONCE per (m,d) into LDS bf16 planes [m][d]
// (row pad 32->40 elems: 80 B stride keeps ds_read_b128 16B-aligned,
// 2-way bank aliasing = free).  Main loop is pure 6x ds_read_b128 +
// 6x MFMA + stores.  bf16 inputs bit-identical to R15.
// grid (32 mG, 16 nG), block 256.  LDS 60 KB -> 2 blocks/CU.
// ===========================================================================
__global__ __launch_bounds__(256) void einsum_mfma(const float* __restrict__ W,
                                                   const float* __restrict__ tau,
                                                   const float* __restrict__ HfR,
                                                   const float* __restrict__ HfI,
                                                   float* __restrict__ out_f) {
    __shared__ __attribute__((aligned(16))) unsigned short sB[6][128][40]; // 61440 B
    const int tid   = threadIdx.x;
    const int mBase = blockIdx.x * 128;
    const int nBase = blockIdx.y * 64;

    const int wv = tid >> 6, lane = tid & 63;
    const int q = lane >> 4, l = lane & 15;
    const int nA = nBase + wv * 16 + l;
    const int d8 = q << 3;
    const float mcF = (float)(mBase + 64);

    // A-side global loads issued first (independent of LDS staging).
    const float4 w0 = *(const float4*)(W   + nA * RANK + d8);
    const float4 w1 = *(const float4*)(W   + nA * RANK + d8 + 4);
    const float4 t0 = *(const float4*)(tau + nA * RANK + d8);
    const float4 t1 = *(const float4*)(tau + nA * RANK + d8 + 4);

    // Cooperative staging: global f32 Hf -> 6 bf16 planes [m][d] in LDS.
    // e -> (d-group of 4, local m). Lanes walk consecutive m: coalesced.
    for (int e = tid; e < 1024; e += 256) {
        const int mloc = e & 127;
        const int d0   = (e >> 7) << 2;          // 0,4,...,28
        const float dlt = (float)mloc - 64.0f;
        const float dq  = dlt * dlt;
        const float* pR = HfR + d0 * M + mBase + mloc;
        const float* pI = HfI + d0 * M + mBase + mloc;
        float r0 = pR[0], r1 = pR[M], r2 = pR[2*M], r3 = pR[3*M];
        float i0 = pI[0], i1 = pI[M], i2 = pI[2*M], i3 = pI[3*M];

        uint2 v;
        v.x = pack_bf16x2(r0, r1);           v.y = pack_bf16x2(r2, r3);
        *(uint2*)&sB[0][mloc][d0] = v;
        v.x = pack_bf16x2(i0, i1);           v.y = pack_bf16x2(i2, i3);
        *(uint2*)&sB[1][mloc][d0] = v;
        v.x = pack_bf16x2(r0*dlt, r1*dlt);   v.y = pack_bf16x2(r2*dlt, r3*dlt);
        *(uint2*)&sB[2][mloc][d0] = v;
        v.x = pack_bf16x2(i0*dlt, i1*dlt);   v.y = pack_bf16x2(i2*dlt, i3*dlt);
        *(uint2*)&sB[3][mloc][d0] = v;
        v.x = pack_bf16x2(r0*dq, r1*dq);     v.y = pack_bf16x2(r2*dq, r3*dq);
        *(uint2*)&sB[4][mloc][d0] = v;
        v.x = pack_bf16x2(i0*dq, i1*dq);     v.y = pack_bf16x2(i2*dq, i3*dq);
        *(uint2*)&sB[5][mloc][d0] = v;
    }

    // A-fragment prologue (unchanged from R15).
    const float wj[8] = {w0.x,w0.y,w0.z,w0.w,w1.x,w1.y,w1.z,w1.w};
    const float tj[8] = {t0.x,t0.y,t0.z,t0.w,t1.x,t1.y,t1.z,t1.w};
    bf16x8 fA[6];
    #pragma unroll
    for (int j = 0; j < 8; ++j) {
        const float sw = softplus_f(wj[j]);
        const float a1 = PHI1 * tj[j];
        float s0, c0; __sincosf(a1 * mcF, &s0, &c0);
        const float R0 = sw * c0,          I0 = sw * s0;
        const float R1 = -a1 * I0,         I1 = a1 * R0;
        const float h  = 0.5f * a1;
        const float R2 = -h * I1,          I2 = h * R1;
        fA[0][j] = bf16_rne(R0);  fA[1][j] = bf16_rne(-I0);
        fA[2][j] = bf16_rne(R1);  fA[3][j] = bf16_rne(-I1);
        fA[4][j] = bf16_rne(R2);  fA[5][j] = bf16_rne(-I2);
    }
    __syncthreads();

    for (int mt = 0; mt < 8; ++mt) {
        const int mL = (mt << 4) + l;
        const bf16x8 b0 = *(const bf16x8*)&sB[0][mL][d8];
        const bf16x8 b1 = *(const bf16x8*)&sB[1][mL][d8];
        const bf16x8 b2 = *(const bf16x8*)&sB[2][mL][d8];
        const bf16x8 b3 = *(const bf16x8*)&sB[3][mL][d8];
        const bf16x8 b4 = *(const bf16x8*)&sB[4][mL][d8];
        const bf16x8 b5 = *(const bf16x8*)&sB[5][mL][d8];

        f32x4 acc = {0.f, 0.f, 0.f, 0.f};
        acc = __builtin_amdgcn_mfma_f32_16x16x32_bf16(fA[0], b0, acc, 0, 0, 0);
        acc = __builtin_amdgcn_mfma_f32_16x16x32_bf16(fA[1], b1, acc, 0, 0, 0);
        acc = __builtin_amdgcn_mfma_f32_16x16x32_bf16(fA[2], b2, acc, 0, 0, 0);
        acc = __builtin_amdgcn_mfma_f32_16x16x32_bf16(fA[3], b3, acc, 0, 0, 0);
        acc = __builtin_amdgcn_mfma_f32_16x16x32_bf16(fA[4], b4, acc, 0, 0, 0);
        acc = __builtin_amdgcn_mfma_f32_16x16x32_bf16(fA[5], b5, acc, 0, 0, 0);

        #pragma unroll
        for (int r = 0; r < 4; ++r)
            out_f[(size_t)(nBase + wv * 16 + (q << 2) + r) * M
                  + mBase + (mt << 4) + l] = acc[r];
    }
}

// ===========================================================================
// dft_fused (no-ws fallback only — validated R5-R9, unchanged).
// ===========================================================================
__global__ __launch_bounds__(256) void dft_fused(const float* __restrict__ H,
                                                 float* __restrict__ HfR,
                                                 float* __restrict__ HfI) {
    __shared__ float  sh[M];
    __shared__ float2 sG[64 * 65];
    const int d = blockIdx.y, tid = threadIdx.x;
    for (int k = tid; k < M; k += 256) sh[k] = softplus_f(H[d * M + k]);
    __syncthreads();

    const int k0 = tid & 63;
    const int rB = (tid >> 6) * 16;
    float twR[16], twI[16], stR[16], stI[16], aR[16], aI[16];
    #pragma unroll
    for (int rr = 0; rr < 16; ++rr) {
        const float ang = (-2.0f * (float)M_PI / 64.0f) * (float)(rB + rr);
        __sincosf(ang, &stI[rr], &stR[rr]);
        twR[rr] = 1.f; twI[rr] = 0.f; aR[rr] = 0.f; aI[rr] = 0.f;
    }
    for (int k1 = 0; k1 < 64; ++k1) {
        const float h = sh[(k1 << 6) + k0];
        #pragma unroll
        for (int rr = 0; rr < 16; ++rr) {
            aR[rr] = fmaf(h, twR[rr], aR[rr]);
            aI[rr] = fmaf(h, twI[rr], aI[rr]);
            const float nR = fmaf(twR[rr], stR[rr], -twI[rr] * stI[rr]);
            const float nI = fmaf(twR[rr], stI[rr],  twI[rr] * stR[rr]);
            twR[rr] = nR; twI[rr] = nI;
        }
    }
    #pragma unroll
    for (int rr = 0; rr < 16; ++rr)
        sG[k0 * 65 + rB + rr] = make_float2(aR[rr], aI[rr]);
    __syncthreads();

    const int mBase = blockIdx.x * 1024;
    for (int j = 0; j < 4; ++j) {
        const int m = mBase + j * 256 + tid;
        const int r = m & 63;
        float ss, sc; __sincosf(PHI1 * (float)m, &ss, &sc);
        float tR_ = 1.f, tI_ = 0.f, accR = 0.f, accI = 0.f;
        #pragma unroll 8
        for (int qq = 0; qq < 64; ++qq) {
            const float2 g = sG[qq * 65 + r];
            accR = fmaf(tR_, g.x, fmaf(-tI_, g.y, accR));
            accI = fmaf(tR_, g.y, fmaf( tI_, g.x, accI));
            const float nR = fmaf(tR_, sc, -tI_ * ss);
            const float nI = fmaf(tR_, ss,  tI_ * sc);
            tR_ = nR; tI_ = nI;
        }
        HfR[d * M + m] = accR;
        HfI[d * M + m] = accI;
    }
}

// ===========================================================================
// VALU einsum v8 (validated R13) — kept for cplx / fallback paths (unchanged).
// ===========================================================================
template <bool CPLX, int U>
__global__ __launch_bounds__(256) void einsum_kernel(const float* __restrict__ W,
                                                     const float* __restrict__ tau,
                                                     const float* __restrict__ HfR,
                                                     const float* __restrict__ HfI,
                                                     float* __restrict__ out_f) {
    constexpr int ROWS = 16 * U;
    constexpr int MT   = 128;
    __shared__ float2 sHf[16 * MT];
    __shared__ float  sW[ROWS][RANK], sT[ROWS][RANK];
    const int tid   = threadIdx.x;
    const int mBase = blockIdx.x * MT;
    const int nBase = blockIdx.y * ROWS;

    for (int i = tid; i < ROWS * RANK; i += 256) {
        const int n_ = i >> 5, dd = i & 31;
        sW[n_][dd] = softplus_f(W[(nBase + n_) * RANK + dd]);
        sT[n_][dd] = tau[(nBase + n_) * RANK + dd];
    }

    const int nl = tid >> 4, chunk = tid & 15;
    const int m0 = mBase + (chunk << 3);

    float accR[U][8], accI[U][8];
    #pragma unroll
    for (int u = 0; u < U; ++u)
        #pragma unroll
        for (int j = 0; j < 8; ++j) { accR[u][j] = 0.f; if (CPLX) accI[u][j] = 0.f; }

    for (int half = 0; half < 2; ++half) {
        __syncthreads();
        for (int e = tid; e < 16 * 64; e += 256) {
            const int dl = e >> 6, p = e & 63;
            const int mm = p << 1;
            const int base = (half * 16 + dl) * M + mBase + mm;
            const float2 r2 = *(const float2*)(HfR + base);
            const float2 q2 = *(const float2*)(HfI + base);
            const int c = mm >> 3, j0 = mm & 7;
            float2* s2 = sHf + (dl << 7);
            s2[(j0 << 4) + c]       = make_float2(r2.x, q2.x);
            s2[((j0 + 1) << 4) + c] = make_float2(r2.y, q2.y);
        }
        __syncthreads();

        #pragma unroll 1
        for (int dl = 0; dl < 16; ++dl) {
            const int dd = (half << 4) + dl;
            float aR_[U], aI_[U], bR_[U], bI_[U], K[U];
            #pragma unroll
            for (int u = 0; u < U; ++u) {
                const float t = sT[nl * U + u][dd], w = sW[nl * U + u][dd];
                const float a1 = PHI1 * t;
                float sp, cp; __sincosf(a1, &sp, &cp);
                float s0, c0; __sincosf(a1 * (float)m0, &s0, &c0);
                aR_[u] = w * c0;
                aI_[u] = w * s0;
                bR_[u] = fmaf(aR_[u], cp, -aI_[u] * sp);
                bI_[u] = fmaf(aI_[u], cp,  aR_[u] * sp);
                K[u]   = 2.0f * cp;
            }
            int idx = (dl << 7) + chunk;
            #pragma unroll
            for (int j = 0; j < 8; ++j) {
                const float2 h = sHf[idx];
                #pragma unroll
                for (int u = 0; u < U; ++u) {
                    accR[u][j] = fmaf(aR_[u], h.x, fmaf(-aI_[u], h.y, accR[u][j]));
                    if (CPLX) accI[u][j] = fmaf(aR_[u], h.y, fmaf(aI_[u], h.x, accI[u][j]));
                    const float nR = fmaf(K[u], bR_[u], -aR_[u]);
                    const float nI = fmaf(K[u], bI_[u], -aI_[u]);
                    aR_[u] = bR_[u]; aI_[u] = bI_[u];
                    bR_[u] = nR;     bI_[u] = nI;
                }
                idx += 16;
            }
        }
    }

    #pragma unroll
    for (int u = 0; u < U; ++u) {
        const int n = nBase + nl * U + u;
        if (CPLX) {
            float2* o2 = ((float2*)out_f) + (size_t)n * M + m0;
            #pragma unroll
            for (int qq = 0; qq < 4; ++qq)
                ((float4*)o2)[qq] = make_float4(accR[u][2*qq], accI[u][2*qq],
                                                accR[u][2*qq+1], accI[u][2*qq+1]);
        } else {
            float* op = out_f + (size_t)n * M + m0;
            ((float4*)op)[0] = make_float4(accR[u][0], accR[u][1], accR[u][2], accR[u][3]);
            ((float4*)op)[1] = make_float4(accR[u][4], accR[u][5], accR[u][6], accR[u][7]);
        }
    }
}

// ===========================================================================
// Tail kernels (no-ws fallback only — dead given 268 MB ws, unchanged).
// ===========================================================================
__global__ __launch_bounds__(256) void tail_real(const float* __restrict__ W,
                                                 const float* __restrict__ tau,
                                                 const float* __restrict__ stashR,
                                                 const float* __restrict__ stashI,
                                                 float* __restrict__ out_f) {
    __shared__ float stR[32 * 32], stI[32 * 32];
    __shared__ float sW[64][RANK], sT[64][RANK];
    const int tid = threadIdx.x;
    const int c0  = blockIdx.x * 32;
    const int nBase = N - 64;
    for (int i = tid; i < 64 * RANK; i += 256) {
        const int n_ = i >> 5, dd = i & 31;
        sW[n_][dd] = softplus_f(W[(nBase + n_) * RANK + dd]);
        sT[n_][dd] = tau[(nBase + n_) * RANK + dd];
    }
    for (int i = tid; i < 32 * 32; i += 256) {
        const int d_ = i >> 5, mm = i & 31;
        stR[i] = stashR[d_ * M + c0 + mm];
        stI[i] = stashI[d_ * M + c0 + mm];
    }
    __syncthreads();
    const int n = tid >> 2, chunk = tid & 3;
    const int m0 = c0 + chunk;
    float acc[8];
    #pragma unroll
    for (int j = 0; j < 8; ++j) acc[j] = 0.f;
    for (int d = 0; d < RANK; ++d) {
        const float t = sT[n][d], w = sW[n][d];
        const float a1 = PHI1 * t;
        float ss, sc; __sincosf(a1 * 4.0f, &ss, &sc);
        float s0, c0f; __sincosf(a1 * (float)m0, &s0, &c0f);
        float tR_ = w * c0f, tI_ = w * s0;
        int idx = (d << 5) + chunk;
        #pragma unroll
        for (int j = 0; j < 8; ++j) {
            acc[j] = fmaf(tR_, stR[idx], fmaf(-tI_, stI[idx], acc[j]));
            const float nR = fmaf(tR_, sc, -tI_ * ss);
            const float nI = fmaf(tR_, ss,  tI_ * sc);
            tR_ = nR; tI_ = nI;
            idx += 4;
        }
    }
    #pragma unroll
    for (int j = 0; j < 8; ++j)
        out_f[(size_t)(nBase + n) * M + m0 + (j << 2)] = acc[j];
}

__global__ __launch_bounds__(256) void tail_cplx(const float* __restrict__ W,
                                                 const float* __restrict__ tau,
                                                 const float* __restrict__ stashR,
                                                 const float* __restrict__ stashI,
                                                 float* __restrict__ out_f) {
    const int nBase = N - 32;
    __shared__ float sW[32][RANK], sT[32][RANK];
    const int tid = threadIdx.x, mBase = blockIdx.x * 256;
    for (int i = tid; i < 32 * RANK; i += 256) {
        const int n_ = i >> 5, dd = i & 31;
        sW[n_][dd] = softplus_f(W[(nBase + n_) * RANK + dd]);
        sT[n_][dd] = tau[(nBase + n_) * RANK + dd];
    }
    const int m = mBase + tid;
    float hr[RANK], hi[RANK];
    #pragma unroll
    for (int d = 0; d < RANK; ++d) { hr[d] = stashR[d * M + m]; hi[d] = stashI[d * M + m]; }
    __syncthreads();
    const float phi = PHI1 * (float)m;
    for (int n_ = 0; n_ < 32; ++n_) {
        float aR = 0.f, aI = 0.f;
        #pragma unroll
        for (int d = 0; d < RANK; ++d) {
            const float t = sT[n_][d], w = sW[n_][d];
            float s, c; __sincosf(t * phi, &s, &c);
            const float cw = c * w, sw = s * w;
            aR = fmaf(cw, hr[d], fmaf(-sw, hi[d], aR));
            aI = fmaf(cw, hi[d], fmaf( sw, hr[d], aI));
        }
        ((float2*)out_f)[(size_t)(nBase + n_) * M + m] = make_float2(aR, aI);
    }
}

// ---------------------------------------------------------------------------
extern "C" void kernel_launch(void* const* d_in, const int* in_sizes, int n_in,
                              void* d_out, int out_size, void* d_ws, size_t ws_size,
                              hipStream_t stream) {
    const float* W   = (const float*)d_in[0];
    const float* H   = (const float*)d_in[1];
    const float* tau = (const float*)d_in[2];
    float* out_f = (float*)d_out;

    const bool   cplx   = (out_size >= 2 * N * M);
    const size_t planeN = (size_t)RANK * M;            // 131072 floats / plane

    if (d_ws != nullptr && ws_size >= 4 * planeN * sizeof(float)) {
        float* HfR = (float*)d_ws;
        float* HfI = HfR + planeN;
        float* GR  = HfI + planeN;
        float* GI  = GR  + planeN;
        dft_s1<<<dim3(8, 32), 256, 0, stream>>>(H, GR, GI);
        dft_s2<<<dim3(16, 32), 256, 0, stream>>>(GR, GI, HfR, HfI);
        if (cplx)
            einsum_kernel<true , 2><<<dim3(32, N / 32), 256, 0, stream>>>(W, tau, HfR, HfI, out_f);
        else
            einsum_mfma<<<dim3(32, 16), 256, 0, stream>>>(W, tau, HfR, HfI, out_f);
    } else if (!cplx) {
        float* HfR = out_f + (size_t)(N - 64) * M;     // stash in last 64 real rows
        float* HfI = HfR + planeN;
        dft_fused<<<dim3(4, 32), 256, 0, stream>>>(H, HfR, HfI);
        einsum_kernel<false, 2><<<dim3(32, (N - 64) / 32), 256, 0, stream>>>(W, tau, HfR, HfI, out_f);
        tail_real<<<dim3(128), 256, 0, stream>>>(W, tau, HfR, HfI, out_f);
    } else {
        float* HfR = out_f + 2 * (size_t)N * M - 2 * planeN;  // last 32 cplx rows
        float* HfI = HfR + planeN;
        dft_fused<<<dim3(4, 32), 256, 0, stream>>>(H, HfR, HfI);
        einsum_kernel<true , 2><<<dim3(32, (N - 32) / 32), 256, 0, stream>>>(W, tau, HfR, HfI, out_f);
        tail_cplx<<<dim3(16), 256, 0, stream>>>(W, tau, HfR, HfI, out_f);
    }
}

// Round 3
// 82.088 us; speedup vs baseline: 1.1209x; 1.0642x over previous
//
#include <hip/hip_runtime.h>
#include <hip/hip_bf16.h>
#include <math.h>

#ifndef M_PI
#define M_PI 3.14159265358979323846
#endif

constexpr int N    = 1024;
constexpr int M    = 4096;
constexpr int RANK = 32;
constexpr float PHI1 = -1.5339807878856412e-3f;   // -2*pi/4096

typedef __attribute__((ext_vector_type(8))) short bf16x8;
typedef __attribute__((ext_vector_type(4))) float f32x4;

// Branch-free fast softplus: max(x,0) + log(1+e^-|x|); HW exp/log, err ~1e-7.
__device__ __forceinline__ float softplus_f(float x) {
    const float t = __expf(-fabsf(x));
    return fmaxf(x, 0.0f) + __logf(1.0f + t);
}

// HW RNE bf16 pair-convert (compiler forms v_cvt_pk_bf16_f32 from scalar casts).
__device__ __forceinline__ unsigned pack_bf16x2(float a, float b) {
    __hip_bfloat162 p;
    p.x = __float2bfloat16(a);
    p.y = __float2bfloat16(b);
    unsigned r;
    __builtin_memcpy(&r, &p, 4);
    return r;
}

// ===========================================================================
// DFT stage 1: G[d][r][k0] = sum_k1 sp(h[d][64k1+k0]) e^{-2pi i k1 r/64}
// grid (8 rG, 32 d), block 256.  (structure validated R10-R17; softplus fast)
// ===========================================================================
__global__ __launch_bounds__(256) void dft_s1(const float* __restrict__ H,
                                              float* __restrict__ GR,
                                              float* __restrict__ GI) {
    __shared__ float sh[M];              // 16 KB
    const int d = blockIdx.y, tid = threadIdx.x;
    const float4* H4 = (const float4*)(H + d * M);
    for (int i = tid; i < M / 4; i += 256) {
        const float4 v = H4[i];
        ((float4*)sh)[i] = make_float4(softplus_f(v.x), softplus_f(v.y),
                                       softplus_f(v.z), softplus_f(v.w));
    }
    __syncthreads();

    const int k0 = tid & 63;
    const int r0 = blockIdx.x * 8 + (tid >> 6) * 2;
    float twR0 = 1.f, twI0 = 0.f, aR0 = 0.f, aI0 = 0.f;
    float twR1 = 1.f, twI1 = 0.f, aR1 = 0.f, aI1 = 0.f;
    float s0, c0, s1, c1;
    __sincosf((-2.0f * (float)M_PI / 64.0f) * (float)r0,       &s0, &c0);
    __sincosf((-2.0f * (float)M_PI / 64.0f) * (float)(r0 + 1), &s1, &c1);

    for (int k1 = 0; k1 < 64; ++k1) {
        const float h = sh[(k1 << 6) + k0];
        aR0 = fmaf(h, twR0, aR0);  aI0 = fmaf(h, twI0, aI0);
        aR1 = fmaf(h, twR1, aR1);  aI1 = fmaf(h, twI1, aI1);
        float nR = fmaf(twR0, c0, -twI0 * s0);
        float nI = fmaf(twR0, s0,  twI0 * c0);
        twR0 = nR; twI0 = nI;
        nR = fmaf(twR1, c1, -twI1 * s1);
        nI = fmaf(twR1, s1,  twI1 * c1);
        twR1 = nR; twI1 = nI;
    }
    const int base = d * 4096 + r0 * 64 + k0;
    GR[base]      = aR0;  GI[base]      = aI0;
    GR[base + 64] = aR1;  GI[base + 64] = aI1;
}

// ===========================================================================
// DFT stage 2: Hf[d][m] = sum_k0 G[d][m&63][k0] e^{-2pi i k0 m/4096}
// grid (16 mG, 32 d), block 256.  (validated R10-R17, unchanged)
// ===========================================================================
__global__ __launch_bounds__(256) void dft_s2(const float* __restrict__ GR,
                                              const float* __restrict__ GI,
                                              float* __restrict__ HfR,
                                              float* __restrict__ HfI) {
    __shared__ float sGR[64 * 65], sGI[64 * 65];   // 33.3 KB
    const int d = blockIdx.y, tid = threadIdx.x;
    const float4* gr4 = (const float4*)(GR + d * 4096);
    const float4* gi4 = (const float4*)(GI + d * 4096);
    for (int i4 = tid; i4 < 1024; i4 += 256) {
        const int r = i4 >> 4, k0 = (i4 & 15) << 2;
        const float4 vr = gr4[i4];
        const float4 vi = gi4[i4];
        const int p = r * 65 + k0;
        sGR[p] = vr.x; sGR[p+1] = vr.y; sGR[p+2] = vr.z; sGR[p+3] = vr.w;
        sGI[p] = vi.x; sGI[p+1] = vi.y; sGI[p+2] = vi.z; sGI[p+3] = vi.w;
    }
    __syncthreads();

    const int m = blockIdx.x * 256 + tid;
    const int rb = (m & 63) * 65;
    float ss, sc; __sincosf(PHI1 * (float)m, &ss, &sc);
    float tR_ = 1.f, tI_ = 0.f, accR = 0.f, accI = 0.f;
    #pragma unroll 8
    for (int k0 = 0; k0 < 64; ++k0) {
        const float gr = sGR[rb + k0], gi = sGI[rb + k0];
        accR = fmaf(tR_, gr, fmaf(-tI_, gi, accR));
        accI = fmaf(tR_, gi, fmaf( tI_, gr, accI));
        const float nR = fmaf(tR_, sc, -tI_ * ss);
        const float nI = fmaf(tR_, ss,  tI_ * sc);
        tR_ = nR; tI_ = nI;
    }
    HfR[d * M + m] = accR;
    HfI[d * M + m] = accI;
}

// ---------------------------------------------------------------------------
// A-side Taylor terms for one (n,d): o = {R0, -I0, R1, -I1, R2, -I2}.
// ---------------------------------------------------------------------------
__device__ __forceinline__ void a_terms(float w, float t, float mcF, float* o) {
    const float sw = softplus_f(w);
    const float a1 = PHI1 * t;
    float s0, c0; __sincosf(a1 * mcF, &s0, &c0);
    const float R0 = sw * c0,  I0 = sw * s0;
    const float R1 = -a1 * I0, I1 = a1 * R0;
    const float h  = 0.5f * a1;
    const float R2 = -h * I1,  I2 = h * R1;
    o[0] = R0; o[1] = -I0; o[2] = R1; o[3] = -I1; o[4] = R2; o[5] = -I2;
}

// ===========================================================================
// MFMA einsum — R19: 64-m tile (LDS 30.7 KB -> 4 blocks/CU, grid 1024 =
// exactly 4/CU resident, 2x the latency-hiding waves of R18's 2/CU) + HW
// bf16 converts (v_cvt_pk via scalar __float2bfloat16 casts; RNE,
// bit-identical to the old manual rounding).  Taylor radius halves
// (|a1*dlt| <= 0.049), so approximation error can only shrink.
// Main loop: 6x ds_read_b128 + 6x MFMA + 4 stores per mt, mt<4.
// grid (64 mG, 16 nG), block 256, __launch_bounds__(256,4).
// ===========================================================================
__global__ __launch_bounds__(256, 4) void einsum_mfma(const float* __restrict__ W,
                                                      const float* __restrict__ tau,
                                                      const float* __restrict__ HfR,
                                                      const float* __restrict__ HfI,
                                                      float* __restrict__ out_f) {
    __shared__ __attribute__((aligned(16))) unsigned short sB[6][64][40]; // 30720 B
    const int tid   = threadIdx.x;
    const int mBase = blockIdx.x * 64;
    const int nBase = blockIdx.y * 64;

    const int wv = tid >> 6, lane = tid & 63;
    const int q = lane >> 4, l = lane & 15;
    const int nA = nBase + wv * 16 + l;
    const int d8 = q << 3;
    const float mcF = (float)(mBase + 32);

    // A-side global loads issued first (independent of LDS staging).
    const float4 w0 = *(const float4*)(W   + nA * RANK + d8);
    const float4 w1 = *(const float4*)(W   + nA * RANK + d8 + 4);
    const float4 t0 = *(const float4*)(tau + nA * RANK + d8);
    const float4 t1 = *(const float4*)(tau + nA * RANK + d8 + 4);

    // Cooperative staging: global f32 Hf -> 6 bf16 planes [m][d] in LDS.
    // Each (m,d) converted exactly once.  Lanes walk consecutive m: coalesced.
    for (int e = tid; e < 512; e += 256) {
        const int mloc = e & 63;
        const int d0   = (e >> 6) << 2;          // 0,4,...,28
        const float dlt = (float)mloc - 32.0f;
        const float dq  = dlt * dlt;
        const float* pR = HfR + d0 * M + mBase + mloc;
        const float* pI = HfI + d0 * M + mBase + mloc;
        float r0 = pR[0], r1 = pR[M], r2 = pR[2*M], r3 = pR[3*M];
        float i0 = pI[0], i1 = pI[M], i2 = pI[2*M], i3 = pI[3*M];

        uint2 v;
        v.x = pack_bf16x2(r0, r1);           v.y = pack_bf16x2(r2, r3);
        *(uint2*)&sB[0][mloc][d0] = v;
        v.x = pack_bf16x2(i0, i1);           v.y = pack_bf16x2(i2, i3);
        *(uint2*)&sB[1][mloc][d0] = v;
        v.x = pack_bf16x2(r0*dlt, r1*dlt);   v.y = pack_bf16x2(r2*dlt, r3*dlt);
        *(uint2*)&sB[2][mloc][d0] = v;
        v.x = pack_bf16x2(i0*dlt, i1*dlt);   v.y = pack_bf16x2(i2*dlt, i3*dlt);
        *(uint2*)&sB[3][mloc][d0] = v;
        v.x = pack_bf16x2(r0*dq, r1*dq);     v.y = pack_bf16x2(r2*dq, r3*dq);
        *(uint2*)&sB[4][mloc][d0] = v;
        v.x = pack_bf16x2(i0*dq, i1*dq);     v.y = pack_bf16x2(i2*dq, i3*dq);
        *(uint2*)&sB[5][mloc][d0] = v;
    }

    // A-fragment prologue: pairwise, packed immediately (short float lifetimes).
    const float wj[8] = {w0.x,w0.y,w0.z,w0.w,w1.x,w1.y,w1.z,w1.w};
    const float tj[8] = {t0.x,t0.y,t0.z,t0.w,t1.x,t1.y,t1.z,t1.w};
    unsigned uA[6][4];
    #pragma unroll
    for (int p = 0; p < 4; ++p) {
        float f0[6], f1[6];
        a_terms(wj[2*p],   tj[2*p],   mcF, f0);
        a_terms(wj[2*p+1], tj[2*p+1], mcF, f1);
        #pragma unroll
        for (int k = 0; k < 6; ++k) uA[k][p] = pack_bf16x2(f0[k], f1[k]);
    }
    bf16x8 fA[6];
    #pragma unroll
    for (int k = 0; k < 6; ++k) __builtin_memcpy(&fA[k], uA[k], 16);
    __syncthreads();

    for (int mt = 0; mt < 4; ++mt) {
        const int mL = (mt << 4) + l;
        const bf16x8 b0 = *(const bf16x8*)&sB[0][mL][d8];
        const bf16x8 b1 = *(const bf16x8*)&sB[1][mL][d8];
        const bf16x8 b2 = *(const bf16x8*)&sB[2][mL][d8];
        const bf16x8 b3 = *(const bf16x8*)&sB[3][mL][d8];
        const bf16x8 b4 = *(const bf16x8*)&sB[4][mL][d8];
        const bf16x8 b5 = *(const bf16x8*)&sB[5][mL][d8];

        f32x4 acc = {0.f, 0.f, 0.f, 0.f};
        acc = __builtin_amdgcn_mfma_f32_16x16x32_bf16(fA[0], b0, acc, 0, 0, 0);
        acc = __builtin_amdgcn_mfma_f32_16x16x32_bf16(fA[1], b1, acc, 0, 0, 0);
        acc = __builtin_amdgcn_mfma_f32_16x16x32_bf16(fA[2], b2, acc, 0, 0, 0);
        acc = __builtin_amdgcn_mfma_f32_16x16x32_bf16(fA[3], b3, acc, 0, 0, 0);
        acc = __builtin_amdgcn_mfma_f32_16x16x32_bf16(fA[4], b4, acc, 0, 0, 0);
        acc = __builtin_amdgcn_mfma_f32_16x16x32_bf16(fA[5], b5, acc, 0, 0, 0);

        #pragma unroll
        for (int r = 0; r < 4; ++r)
            out_f[(size_t)(nBase + wv * 16 + (q << 2) + r) * M
                  + mBase + (mt << 4) + l] = acc[r];
    }
}

// ===========================================================================
// dft_fused (no-ws fallback only — validated R5-R9, unchanged).
// ===========================================================================
__global__ __launch_bounds__(256) void dft_fused(const float* __restrict__ H,
                                                 float* __restrict__ HfR,
                                                 float* __restrict__ HfI) {
    __shared__ float  sh[M];
    __shared__ float2 sG[64 * 65];
    const int d = blockIdx.y, tid = threadIdx.x;
    for (int k = tid; k < M; k += 256) sh[k] = softplus_f(H[d * M + k]);
    __syncthreads();

    const int k0 = tid & 63;
    const int rB = (tid >> 6) * 16;
    float twR[16], twI[16], stR[16], stI[16], aR[16], aI[16];
    #pragma unroll
    for (int rr = 0; rr < 16; ++rr) {
        const float ang = (-2.0f * (float)M_PI / 64.0f) * (float)(rB + rr);
        __sincosf(ang, &stI[rr], &stR[rr]);
        twR[rr] = 1.f; twI[rr] = 0.f; aR[rr] = 0.f; aI[rr] = 0.f;
    }
    for (int k1 = 0; k1 < 64; ++k1) {
        const float h = sh[(k1 << 6) + k0];
        #pragma unroll
        for (int rr = 0; rr < 16; ++rr) {
            aR[rr] = fmaf(h, twR[rr], aR[rr]);
            aI[rr] = fmaf(h, twI[rr], aI[rr]);
            const float nR = fmaf(twR[rr], stR[rr], -twI[rr] * stI[rr]);
            const float nI = fmaf(twR[rr], stI[rr],  twI[rr] * stR[rr]);
            twR[rr] = nR; twI[rr] = nI;
        }
    }
    #pragma unroll
    for (int rr = 0; rr < 16; ++rr)
        sG[k0 * 65 + rB + rr] = make_float2(aR[rr], aI[rr]);
    __syncthreads();

    const int mBase = blockIdx.x * 1024;
    for (int j = 0; j < 4; ++j) {
        const int m = mBase + j * 256 + tid;
        const int r = m & 63;
        float ss, sc; __sincosf(PHI1 * (float)m, &ss, &sc);
        float tR_ = 1.f, tI_ = 0.f, accR = 0.f, accI = 0.f;
        #pragma unroll 8
        for (int qq = 0; qq < 64; ++qq) {
            const float2 g = sG[qq * 65 + r];
            accR = fmaf(tR_, g.x, fmaf(-tI_, g.y, accR));
            accI = fmaf(tR_, g.y, fmaf( tI_, g.x, accI));
            const float nR = fmaf(tR_, sc, -tI_ * ss);
            const float nI = fmaf(tR_, ss,  tI_ * sc);
            tR_ = nR; tI_ = nI;
        }
        HfR[d * M + m] = accR;
        HfI[d * M + m] = accI;
    }
}

// ===========================================================================
// VALU einsum v8 (validated R13) — kept for cplx / fallback paths (unchanged).
// ===========================================================================
template <bool CPLX, int U>
__global__ __launch_bounds__(256) void einsum_kernel(const float* __restrict__ W,
                                                     const float* __restrict__ tau,
                                                     const float* __restrict__ HfR,
                                                     const float* __restrict__ HfI,
                                                     float* __restrict__ out_f) {
    constexpr int ROWS = 16 * U;
    constexpr int MT   = 128;
    __shared__ float2 sHf[16 * MT];
    __shared__ float  sW[ROWS][RANK], sT[ROWS][RANK];
    const int tid   = threadIdx.x;
    const int mBase = blockIdx.x * MT;
    const int nBase = blockIdx.y * ROWS;

    for (int i = tid; i < ROWS * RANK; i += 256) {
        const int n_ = i >> 5, dd = i & 31;
        sW[n_][dd] = softplus_f(W[(nBase + n_) * RANK + dd]);
        sT[n_][dd] = tau[(nBase + n_) * RANK + dd];
    }

    const int nl = tid >> 4, chunk = tid & 15;
    const int m0 = mBase + (chunk << 3);

    float accR[U][8], accI[U][8];
    #pragma unroll
    for (int u = 0; u < U; ++u)
        #pragma unroll
        for (int j = 0; j < 8; ++j) { accR[u][j] = 0.f; if (CPLX) accI[u][j] = 0.f; }

    for (int half = 0; half < 2; ++half) {
        __syncthreads();
        for (int e = tid; e < 16 * 64; e += 256) {
            const int dl = e >> 6, p = e & 63;
            const int mm = p << 1;
            const int base = (half * 16 + dl) * M + mBase + mm;
            const float2 r2 = *(const float2*)(HfR + base);
            const float2 q2 = *(const float2*)(HfI + base);
            const int c = mm >> 3, j0 = mm & 7;
            float2* s2 = sHf + (dl << 7);
            s2[(j0 << 4) + c]       = make_float2(r2.x, q2.x);
            s2[((j0 + 1) << 4) + c] = make_float2(r2.y, q2.y);
        }
        __syncthreads();

        #pragma unroll 1
        for (int dl = 0; dl < 16; ++dl) {
            const int dd = (half << 4) + dl;
            float aR_[U], aI_[U], bR_[U], bI_[U], K[U];
            #pragma unroll
            for (int u = 0; u < U; ++u) {
                const float t = sT[nl * U + u][dd], w = sW[nl * U + u][dd];
                const float a1 = PHI1 * t;
                float sp, cp; __sincosf(a1, &sp, &cp);
                float s0, c0; __sincosf(a1 * (float)m0, &s0, &c0);
                aR_[u] = w * c0;
                aI_[u] = w * s0;
                bR_[u] = fmaf(aR_[u], cp, -aI_[u] * sp);
                bI_[u] = fmaf(aI_[u], cp,  aR_[u] * sp);
                K[u]   = 2.0f * cp;
            }
            int idx = (dl << 7) + chunk;
            #pragma unroll
            for (int j = 0; j < 8; ++j) {
                const float2 h = sHf[idx];
                #pragma unroll
                for (int u = 0; u < U; ++u) {
                    accR[u][j] = fmaf(aR_[u], h.x, fmaf(-aI_[u], h.y, accR[u][j]));
                    if (CPLX) accI[u][j] = fmaf(aR_[u], h.y, fmaf(aI_[u], h.x, accI[u][j]));
                    const float nR = fmaf(K[u], bR_[u], -aR_[u]);
                    const float nI = fmaf(K[u], bI_[u], -aI_[u]);
                    aR_[u] = bR_[u]; aI_[u] = bI_[u];
                    bR_[u] = nR;     bI_[u] = nI;
                }
                idx += 16;
            }
        }
    }

    #pragma unroll
    for (int u = 0; u < U; ++u) {
        const int n = nBase + nl * U + u;
        if (CPLX) {
            float2* o2 = ((float2*)out_f) + (size_t)n * M + m0;
            #pragma unroll
            for (int qq = 0; qq < 4; ++qq)
                ((float4*)o2)[qq] = make_float4(accR[u][2*qq], accI[u][2*qq],
                                                accR[u][2*qq+1], accI[u][2*qq+1]);
        } else {
            float* op = out_f + (size_t)n * M + m0;
            ((float4*)op)[0] = make_float4(accR[u][0], accR[u][1], accR[u][2], accR[u][3]);
            ((float4*)op)[1] = make_float4(accR[u][4], accR[u][5], accR[u][6], accR[u][7]);
        }
    }
}

// ===========================================================================
// Tail kernels (no-ws fallback only — dead given 268 MB ws, unchanged).
// ===========================================================================
__global__ __launch_bounds__(256) void tail_real(const float* __restrict__ W,
                                                 const float* __restrict__ tau,
                                                 const float* __restrict__ stashR,
                                                 const float* __restrict__ stashI,
                                                 float* __restrict__ out_f) {
    __shared__ float stR[32 * 32], stI[32 * 32];
    __shared__ float sW[64][RANK], sT[64][RANK];
    const int tid = threadIdx.x;
    const int c0  = blockIdx.x * 32;
    const int nBase = N - 64;
    for (int i = tid; i < 64 * RANK; i += 256) {
        const int n_ = i >> 5, dd = i & 31;
        sW[n_][dd] = softplus_f(W[(nBase + n_) * RANK + dd]);
        sT[n_][dd] = tau[(nBase + n_) * RANK + dd];
    }
    for (int i = tid; i < 32 * 32; i += 256) {
        const int d_ = i >> 5, mm = i & 31;
        stR[i] = stashR[d_ * M + c0 + mm];
        stI[i] = stashI[d_ * M + c0 + mm];
    }
    __syncthreads();
    const int n = tid >> 2, chunk = tid & 3;
    const int m0 = c0 + chunk;
    float acc[8];
    #pragma unroll
    for (int j = 0; j < 8; ++j) acc[j] = 0.f;
    for (int d = 0; d < RANK; ++d) {
        const float t = sT[n][d], w = sW[n][d];
        const float a1 = PHI1 * t;
        float ss, sc; __sincosf(a1 * 4.0f, &ss, &sc);
        float s0, c0f; __sincosf(a1 * (float)m0, &s0, &c0f);
        float tR_ = w * c0f, tI_ = w * s0;
        int idx = (d << 5) + chunk;
        #pragma unroll
        for (int j = 0; j < 8; ++j) {
            acc[j] = fmaf(tR_, stR[idx], fmaf(-tI_, stI[idx], acc[j]));
            const float nR = fmaf(tR_, sc, -tI_ * ss);
            const float nI = fmaf(tR_, ss,  tI_ * sc);
            tR_ = nR; tI_ = nI;
            idx += 4;
        }
    }
    #pragma unroll
    for (int j = 0; j < 8; ++j)
        out_f[(size_t)(nBase + n) * M + m0 + (j << 2)] = acc[j];
}

__global__ __launch_bounds__(256) void tail_cplx(const float* __restrict__ W,
                                                 const float* __restrict__ tau,
                                                 const float* __restrict__ stashR,
                                                 const float* __restrict__ stashI,
                                                 float* __restrict__ out_f) {
    const int nBase = N - 32;
    __shared__ float sW[32][RANK], sT[32][RANK];
    const int tid = threadIdx.x, mBase = blockIdx.x * 256;
    for (int i = tid; i < 32 * RANK; i += 256) {
        const int n_ = i >> 5, dd = i & 31;
        sW[n_][dd] = softplus_f(W[(nBase + n_) * RANK + dd]);
        sT[n_][dd] = tau[(nBase + n_) * RANK + dd];
    }
    const int m = mBase + tid;
    float hr[RANK], hi[RANK];
    #pragma unroll
    for (int d = 0; d < RANK; ++d) { hr[d] = stashR[d * M + m]; hi[d] = stashI[d * M + m]; }
    __syncthreads();
    const float phi = PHI1 * (float)m;
    for (int n_ = 0; n_ < 32; ++n_) {
        float aR = 0.f, aI = 0.f;
        #pragma unroll
        for (int d = 0; d < RANK; ++d) {
            const float t = sT[n_][d], w = sW[n_][d];
            float s, c; __sincosf(t * phi, &s, &c);
            const float cw = c * w, sw = s * w;
            aR = fmaf(cw, hr[d], fmaf(-sw, hi[d], aR));
            aI = fmaf(cw, hi[d], fmaf( sw, hr[d], aI));
        }
        ((float2*)out_f)[(size_t)(nBase + n_) * M + m] = make_float2(aR, aI);
    }
}

// ---------------------------------------------------------------------------
extern "C" void kernel_launch(void* const* d_in, const int* in_sizes, int n_in,
                              void* d_out, int out_size, void* d_ws, size_t ws_size,
                              hipStream_t stream) {
    const float* W   = (const float*)d_in[0];
    const float* H   = (const float*)d_in[1];
    const float* tau = (const float*)d_in[2];
    float* out_f = (float*)d_out;

    const bool   cplx   = (out_size >= 2 * N * M);
    const size_t planeN = (size_t)RANK * M;            // 131072 floats / plane

    if (d_ws != nullptr && ws_size >= 4 * planeN * sizeof(float)) {
        float* HfR = (float*)d_ws;
        float* HfI = HfR + planeN;
        float* GR  = HfI + planeN;
        float* GI  = GR  + planeN;
        dft_s1<<<dim3(8, 32), 256, 0, stream>>>(H, GR, GI);
        dft_s2<<<dim3(16, 32), 256, 0, stream>>>(GR, GI, HfR, HfI);
        if (cplx)
            einsum_kernel<true , 2><<<dim3(32, N / 32), 256, 0, stream>>>(W, tau, HfR, HfI, out_f);
        else
            einsum_mfma<<<dim3(64, 16), 256, 0, stream>>>(W, tau, HfR, HfI, out_f);
    } else if (!cplx) {
        float* HfR = out_f + (size_t)(N - 64) * M;     // stash in last 64 real rows
        float* HfI = HfR + planeN;
        dft_fused<<<dim3(4, 32), 256, 0, stream>>>(H, HfR, HfI);
        einsum_kernel<false, 2><<<dim3(32, (N - 64) / 32), 256, 0, stream>>>(W, tau, HfR, HfI, out_f);
        tail_real<<<dim3(128), 256, 0, stream>>>(W, tau, HfR, HfI, out_f);
    } else {
        float* HfR = out_f + 2 * (size_t)N * M - 2 * planeN;  // last 32 cplx rows
        float* HfI = HfR + planeN;
        dft_fused<<<dim3(4, 32), 256, 0, stream>>>(H, HfR, HfI);
        einsum_kernel<true , 2><<<dim3(32, (N - 32) / 32), 256, 0, stream>>>(W, tau, HfR, HfI, out_f);
        tail_cplx<<<dim3(16), 256, 0, stream>>>(W, tau, HfR, HfI, out_f);
    }
}

// Round 4
// 81.579 us; speedup vs baseline: 1.1279x; 1.0062x over previous
//
#include <hip/hip_runtime.h>
#include <hip/hip_cooperative_groups.h>
#include <hip/hip_bf16.h>
#include <math.h>

#ifndef M_PI
#define M_PI 3.14159265358979323846
#endif

namespace cg = cooperative_groups;

constexpr int N    = 1024;
constexpr int M    = 4096;
constexpr int RANK = 32;
constexpr float PHI1 = -1.5339807878856412e-3f;   // -2*pi/4096

typedef __attribute__((ext_vector_type(8))) short bf16x8;
typedef __attribute__((ext_vector_type(4))) float f32x4;

// Branch-free fast softplus: max(x,0) + log(1+e^-|x|); HW exp/log, err ~1e-7.
__device__ __forceinline__ float softplus_f(float x) {
    const float t = __expf(-fabsf(x));
    return fmaxf(x, 0.0f) + __logf(1.0f + t);
}

// HW RNE bf16 pair-convert (compiler forms v_cvt_pk_bf16_f32 from scalar casts).
__device__ __forceinline__ unsigned pack_bf16x2(float a, float b) {
    __hip_bfloat162 p;
    p.x = __float2bfloat16(a);
    p.y = __float2bfloat16(b);
    unsigned r;
    __builtin_memcpy(&r, &p, 4);
    return r;
}

// ---------------------------------------------------------------------------
// A-side Taylor terms for one (n,d): o = {R0, -I0, R1, -I1, R2, -I2}.
// ---------------------------------------------------------------------------
__device__ __forceinline__ void a_terms(float w, float t, float mcF, float* o) {
    const float sw = softplus_f(w);
    const float a1 = PHI1 * t;
    float s0, c0; __sincosf(a1 * mcF, &s0, &c0);
    const float R0 = sw * c0,  I0 = sw * s0;
    const float R1 = -a1 * I0, I1 = a1 * R0;
    const float h  = 0.5f * a1;
    const float R2 = -h * I1,  I2 = h * R1;
    o[0] = R0; o[1] = -I0; o[2] = R1; o[3] = -I1; o[4] = R2; o[5] = -I2;
}

// ===========================================================================
// R20 cooperative mega-kernel: s1 -> grid.sync -> s2 -> grid.sync -> einsum.
// Replaces 3 dependent launches (2 launch gaps + 2 full drains) with one.
// grid 1024 x 256.  LDS = 33280 B union (s1 16K / s2 33.3K / einsum 30.7K)
// -> exactly 4 blocks/CU x 256 CU = 1024 co-resident.  VGPR pinned <=128 by
// __launch_bounds__(256,4).  All arithmetic bit-identical to R19.
// ===========================================================================
__global__ __launch_bounds__(256, 4) void mega_real(const float* __restrict__ W,
                                                    const float* __restrict__ tau,
                                                    const float* __restrict__ H,
                                                    float* __restrict__ GR,
                                                    float* __restrict__ GI,
                                                    float* __restrict__ HfR,
                                                    float* __restrict__ HfI,
                                                    float* __restrict__ out_f) {
    __shared__ __attribute__((aligned(16))) char smem[64 * 65 * 8];   // 33280 B
    const int tid = threadIdx.x;
    const int bx  = blockIdx.x;
    cg::grid_group grid = cg::this_grid();

    // ---- phase 1: DFT stage 1.  blocks 0..511 = (16 rG, 32 d), 4 r each.
    if (bx < 512) {
        float* sh = (float*)smem;
        const int d  = bx >> 4;
        const int rG = bx & 15;
        const float4* H4 = (const float4*)(H + d * M);
        for (int i = tid; i < M / 4; i += 256) {
            const float4 v = H4[i];
            ((float4*)sh)[i] = make_float4(softplus_f(v.x), softplus_f(v.y),
                                           softplus_f(v.z), softplus_f(v.w));
        }
        __syncthreads();
        const int k0 = tid & 63;
        const int r0 = rG * 4 + (tid >> 6);
        float s0, c0;
        __sincosf((-2.0f * (float)M_PI / 64.0f) * (float)r0, &s0, &c0);
        float twR = 1.f, twI = 0.f, aR = 0.f, aI = 0.f;
        for (int k1 = 0; k1 < 64; ++k1) {
            const float h = sh[(k1 << 6) + k0];
            aR = fmaf(h, twR, aR);  aI = fmaf(h, twI, aI);
            const float nR = fmaf(twR, c0, -twI * s0);
            const float nI = fmaf(twR, s0,  twI * c0);
            twR = nR; twI = nI;
        }
        const int base = d * 4096 + r0 * 64 + k0;
        GR[base] = aR;  GI[base] = aI;
    }
    __threadfence();
    grid.sync();

    // ---- phase 2: DFT stage 2.  blocks 0..511 = (16 mG, 32 d), 256 m each.
    if (bx < 512) {
        float* sGR = (float*)smem;
        float* sGI = sGR + 64 * 65;
        const int d  = bx >> 4;
        const int mG = bx & 15;
        const float4* gr4 = (const float4*)(GR + d * 4096);
        const float4* gi4 = (const float4*)(GI + d * 4096);
        for (int i4 = tid; i4 < 1024; i4 += 256) {
            const int r = i4 >> 4, k0 = (i4 & 15) << 2;
            const float4 vr = gr4[i4];
            const float4 vi = gi4[i4];
            const int p = r * 65 + k0;
            sGR[p] = vr.x; sGR[p+1] = vr.y; sGR[p+2] = vr.z; sGR[p+3] = vr.w;
            sGI[p] = vi.x; sGI[p+1] = vi.y; sGI[p+2] = vi.z; sGI[p+3] = vi.w;
        }
        __syncthreads();
        const int m  = mG * 256 + tid;
        const int rb = (m & 63) * 65;
        float ss, sc; __sincosf(PHI1 * (float)m, &ss, &sc);
        float tR_ = 1.f, tI_ = 0.f, accR = 0.f, accI = 0.f;
        #pragma unroll 8
        for (int k0 = 0; k0 < 64; ++k0) {
            const float gr = sGR[rb + k0], gi = sGI[rb + k0];
            accR = fmaf(tR_, gr, fmaf(-tI_, gi, accR));
            accI = fmaf(tR_, gi, fmaf( tI_, gr, accI));
            const float nR = fmaf(tR_, sc, -tI_ * ss);
            const float nI = fmaf(tR_, ss,  tI_ * sc);
            tR_ = nR; tI_ = nI;
        }
        HfR[d * M + m] = accR;
        HfI[d * M + m] = accI;
    }
    __threadfence();
    grid.sync();

    // ---- phase 3: einsum (all 1024 blocks = (64 mG, 16 nG)).  R19 body.
    typedef unsigned short (*sBp_t)[64][40];
    sBp_t sB = (sBp_t)smem;                           // sB[6][64][40], 30720 B
    const int mBase = (bx & 63) << 6;
    const int nBase = (bx >> 6) << 6;
    const int wv = tid >> 6, lane = tid & 63;
    const int q = lane >> 4, l = lane & 15;
    const int nA = nBase + wv * 16 + l;
    const int d8 = q << 3;
    const float mcF = (float)(mBase + 32);

    const float4 w0 = *(const float4*)(W   + nA * RANK + d8);
    const float4 w1 = *(const float4*)(W   + nA * RANK + d8 + 4);
    const float4 t0 = *(const float4*)(tau + nA * RANK + d8);
    const float4 t1 = *(const float4*)(tau + nA * RANK + d8 + 4);

    for (int e = tid; e < 512; e += 256) {
        const int mloc = e & 63;
        const int d0   = (e >> 6) << 2;
        const float dlt = (float)mloc - 32.0f;
        const float dq  = dlt * dlt;
        const float* pR = HfR + d0 * M + mBase + mloc;
        const float* pI = HfI + d0 * M + mBase + mloc;
        float r0 = pR[0], r1 = pR[M], r2 = pR[2*M], r3 = pR[3*M];
        float i0 = pI[0], i1 = pI[M], i2 = pI[2*M], i3 = pI[3*M];

        uint2 v;
        v.x = pack_bf16x2(r0, r1);           v.y = pack_bf16x2(r2, r3);
        *(uint2*)&sB[0][mloc][d0] = v;
        v.x = pack_bf16x2(i0, i1);           v.y = pack_bf16x2(i2, i3);
        *(uint2*)&sB[1][mloc][d0] = v;
        v.x = pack_bf16x2(r0*dlt, r1*dlt);   v.y = pack_bf16x2(r2*dlt, r3*dlt);
        *(uint2*)&sB[2][mloc][d0] = v;
        v.x = pack_bf16x2(i0*dlt, i1*dlt);   v.y = pack_bf16x2(i2*dlt, i3*dlt);
        *(uint2*)&sB[3][mloc][d0] = v;
        v.x = pack_bf16x2(r0*dq, r1*dq);     v.y = pack_bf16x2(r2*dq, r3*dq);
        *(uint2*)&sB[4][mloc][d0] = v;
        v.x = pack_bf16x2(i0*dq, i1*dq);     v.y = pack_bf16x2(i2*dq, i3*dq);
        *(uint2*)&sB[5][mloc][d0] = v;
    }

    const float wj[8] = {w0.x,w0.y,w0.z,w0.w,w1.x,w1.y,w1.z,w1.w};
    const float tj[8] = {t0.x,t0.y,t0.z,t0.w,t1.x,t1.y,t1.z,t1.w};
    unsigned uA[6][4];
    #pragma unroll
    for (int p = 0; p < 4; ++p) {
        float f0[6], f1[6];
        a_terms(wj[2*p],   tj[2*p],   mcF, f0);
        a_terms(wj[2*p+1], tj[2*p+1], mcF, f1);
        #pragma unroll
        for (int k = 0; k < 6; ++k) uA[k][p] = pack_bf16x2(f0[k], f1[k]);
    }
    bf16x8 fA[6];
    #pragma unroll
    for (int k = 0; k < 6; ++k) __builtin_memcpy(&fA[k], uA[k], 16);
    __syncthreads();

    for (int mt = 0; mt < 4; ++mt) {
        const int mL = (mt << 4) + l;
        const bf16x8 b0 = *(const bf16x8*)&sB[0][mL][d8];
        const bf16x8 b1 = *(const bf16x8*)&sB[1][mL][d8];
        const bf16x8 b2 = *(const bf16x8*)&sB[2][mL][d8];
        const bf16x8 b3 = *(const bf16x8*)&sB[3][mL][d8];
        const bf16x8 b4 = *(const bf16x8*)&sB[4][mL][d8];
        const bf16x8 b5 = *(const bf16x8*)&sB[5][mL][d8];

        f32x4 acc = {0.f, 0.f, 0.f, 0.f};
        acc = __builtin_amdgcn_mfma_f32_16x16x32_bf16(fA[0], b0, acc, 0, 0, 0);
        acc = __builtin_amdgcn_mfma_f32_16x16x32_bf16(fA[1], b1, acc, 0, 0, 0);
        acc = __builtin_amdgcn_mfma_f32_16x16x32_bf16(fA[2], b2, acc, 0, 0, 0);
        acc = __builtin_amdgcn_mfma_f32_16x16x32_bf16(fA[3], b3, acc, 0, 0, 0);
        acc = __builtin_amdgcn_mfma_f32_16x16x32_bf16(fA[4], b4, acc, 0, 0, 0);
        acc = __builtin_amdgcn_mfma_f32_16x16x32_bf16(fA[5], b5, acc, 0, 0, 0);

        #pragma unroll
        for (int r = 0; r < 4; ++r)
            out_f[(size_t)(nBase + wv * 16 + (q << 2) + r) * M
                  + mBase + (mt << 4) + l] = acc[r];
    }
}

// ===========================================================================
// DFT stage 1 (fallback path; validated R10-R19).
// ===========================================================================
__global__ __launch_bounds__(256) void dft_s1(const float* __restrict__ H,
                                              float* __restrict__ GR,
                                              float* __restrict__ GI) {
    __shared__ float sh[M];              // 16 KB
    const int d = blockIdx.y, tid = threadIdx.x;
    const float4* H4 = (const float4*)(H + d * M);
    for (int i = tid; i < M / 4; i += 256) {
        const float4 v = H4[i];
        ((float4*)sh)[i] = make_float4(softplus_f(v.x), softplus_f(v.y),
                                       softplus_f(v.z), softplus_f(v.w));
    }
    __syncthreads();

    const int k0 = tid & 63;
    const int r0 = blockIdx.x * 8 + (tid >> 6) * 2;
    float twR0 = 1.f, twI0 = 0.f, aR0 = 0.f, aI0 = 0.f;
    float twR1 = 1.f, twI1 = 0.f, aR1 = 0.f, aI1 = 0.f;
    float s0, c0, s1, c1;
    __sincosf((-2.0f * (float)M_PI / 64.0f) * (float)r0,       &s0, &c0);
    __sincosf((-2.0f * (float)M_PI / 64.0f) * (float)(r0 + 1), &s1, &c1);

    for (int k1 = 0; k1 < 64; ++k1) {
        const float h = sh[(k1 << 6) + k0];
        aR0 = fmaf(h, twR0, aR0);  aI0 = fmaf(h, twI0, aI0);
        aR1 = fmaf(h, twR1, aR1);  aI1 = fmaf(h, twI1, aI1);
        float nR = fmaf(twR0, c0, -twI0 * s0);
        float nI = fmaf(twR0, s0,  twI0 * c0);
        twR0 = nR; twI0 = nI;
        nR = fmaf(twR1, c1, -twI1 * s1);
        nI = fmaf(twR1, s1,  twI1 * c1);
        twR1 = nR; twI1 = nI;
    }
    const int base = d * 4096 + r0 * 64 + k0;
    GR[base]      = aR0;  GI[base]      = aI0;
    GR[base + 64] = aR1;  GI[base + 64] = aI1;
}

// ===========================================================================
// DFT stage 2 (fallback path; validated R10-R19).
// ===========================================================================
__global__ __launch_bounds__(256) void dft_s2(const float* __restrict__ GR,
                                              const float* __restrict__ GI,
                                              float* __restrict__ HfR,
                                              float* __restrict__ HfI) {
    __shared__ float sGR[64 * 65], sGI[64 * 65];   // 33.3 KB
    const int d = blockIdx.y, tid = threadIdx.x;
    const float4* gr4 = (const float4*)(GR + d * 4096);
    const float4* gi4 = (const float4*)(GI + d * 4096);
    for (int i4 = tid; i4 < 1024; i4 += 256) {
        const int r = i4 >> 4, k0 = (i4 & 15) << 2;
        const float4 vr = gr4[i4];
        const float4 vi = gi4[i4];
        const int p = r * 65 + k0;
        sGR[p] = vr.x; sGR[p+1] = vr.y; sGR[p+2] = vr.z; sGR[p+3] = vr.w;
        sGI[p] = vi.x; sGI[p+1] = vi.y; sGI[p+2] = vi.z; sGI[p+3] = vi.w;
    }
    __syncthreads();

    const int m = blockIdx.x * 256 + tid;
    const int rb = (m & 63) * 65;
    float ss, sc; __sincosf(PHI1 * (float)m, &ss, &sc);
    float tR_ = 1.f, tI_ = 0.f, accR = 0.f, accI = 0.f;
    #pragma unroll 8
    for (int k0 = 0; k0 < 64; ++k0) {
        const float gr = sGR[rb + k0], gi = sGI[rb + k0];
        accR = fmaf(tR_, gr, fmaf(-tI_, gi, accR));
        accI = fmaf(tR_, gi, fmaf( tI_, gr, accI));
        const float nR = fmaf(tR_, sc, -tI_ * ss);
        const float nI = fmaf(tR_, ss,  tI_ * sc);
        tR_ = nR; tI_ = nI;
    }
    HfR[d * M + m] = accR;
    HfI[d * M + m] = accI;
}

// ===========================================================================
// MFMA einsum (fallback path; R19, validated 82.1 us).
// ===========================================================================
__global__ __launch_bounds__(256, 4) void einsum_mfma(const float* __restrict__ W,
                                                      const float* __restrict__ tau,
                                                      const float* __restrict__ HfR,
                                                      const float* __restrict__ HfI,
                                                      float* __restrict__ out_f) {
    __shared__ __attribute__((aligned(16))) unsigned short sB[6][64][40]; // 30720 B
    const int tid   = threadIdx.x;
    const int mBase = blockIdx.x * 64;
    const int nBase = blockIdx.y * 64;

    const int wv = tid >> 6, lane = tid & 63;
    const int q = lane >> 4, l = lane & 15;
    const int nA = nBase + wv * 16 + l;
    const int d8 = q << 3;
    const float mcF = (float)(mBase + 32);

    const float4 w0 = *(const float4*)(W   + nA * RANK + d8);
    const float4 w1 = *(const float4*)(W   + nA * RANK + d8 + 4);
    const float4 t0 = *(const float4*)(tau + nA * RANK + d8);
    const float4 t1 = *(const float4*)(tau + nA * RANK + d8 + 4);

    for (int e = tid; e < 512; e += 256) {
        const int mloc = e & 63;
        const int d0   = (e >> 6) << 2;
        const float dlt = (float)mloc - 32.0f;
        const float dq  = dlt * dlt;
        const float* pR = HfR + d0 * M + mBase + mloc;
        const float* pI = HfI + d0 * M + mBase + mloc;
        float r0 = pR[0], r1 = pR[M], r2 = pR[2*M], r3 = pR[3*M];
        float i0 = pI[0], i1 = pI[M], i2 = pI[2*M], i3 = pI[3*M];

        uint2 v;
        v.x = pack_bf16x2(r0, r1);           v.y = pack_bf16x2(r2, r3);
        *(uint2*)&sB[0][mloc][d0] = v;
        v.x = pack_bf16x2(i0, i1);           v.y = pack_bf16x2(i2, i3);
        *(uint2*)&sB[1][mloc][d0] = v;
        v.x = pack_bf16x2(r0*dlt, r1*dlt);   v.y = pack_bf16x2(r2*dlt, r3*dlt);
        *(uint2*)&sB[2][mloc][d0] = v;
        v.x = pack_bf16x2(i0*dlt, i1*dlt);   v.y = pack_bf16x2(i2*dlt, i3*dlt);
        *(uint2*)&sB[3][mloc][d0] = v;
        v.x = pack_bf16x2(r0*dq, r1*dq);     v.y = pack_bf16x2(r2*dq, r3*dq);
        *(uint2*)&sB[4][mloc][d0] = v;
        v.x = pack_bf16x2(i0*dq, i1*dq);     v.y = pack_bf16x2(i2*dq, i3*dq);
        *(uint2*)&sB[5][mloc][d0] = v;
    }

    const float wj[8] = {w0.x,w0.y,w0.z,w0.w,w1.x,w1.y,w1.z,w1.w};
    const float tj[8] = {t0.x,t0.y,t0.z,t0.w,t1.x,t1.y,t1.z,t1.w};
    unsigned uA[6][4];
    #pragma unroll
    for (int p = 0; p < 4; ++p) {
        float f0[6], f1[6];
        a_terms(wj[2*p],   tj[2*p],   mcF, f0);
        a_terms(wj[2*p+1], tj[2*p+1], mcF, f1);
        #pragma unroll
        for (int k = 0; k < 6; ++k) uA[k][p] = pack_bf16x2(f0[k], f1[k]);
    }
    bf16x8 fA[6];
    #pragma unroll
    for (int k = 0; k < 6; ++k) __builtin_memcpy(&fA[k], uA[k], 16);
    __syncthreads();

    for (int mt = 0; mt < 4; ++mt) {
        const int mL = (mt << 4) + l;
        const bf16x8 b0 = *(const bf16x8*)&sB[0][mL][d8];
        const bf16x8 b1 = *(const bf16x8*)&sB[1][mL][d8];
        const bf16x8 b2 = *(const bf16x8*)&sB[2][mL][d8];
        const bf16x8 b3 = *(const bf16x8*)&sB[3][mL][d8];
        const bf16x8 b4 = *(const bf16x8*)&sB[4][mL][d8];
        const bf16x8 b5 = *(const bf16x8*)&sB[5][mL][d8];

        f32x4 acc = {0.f, 0.f, 0.f, 0.f};
        acc = __builtin_amdgcn_mfma_f32_16x16x32_bf16(fA[0], b0, acc, 0, 0, 0);
        acc = __builtin_amdgcn_mfma_f32_16x16x32_bf16(fA[1], b1, acc, 0, 0, 0);
        acc = __builtin_amdgcn_mfma_f32_16x16x32_bf16(fA[2], b2, acc, 0, 0, 0);
        acc = __builtin_amdgcn_mfma_f32_16x16x32_bf16(fA[3], b3, acc, 0, 0, 0);
        acc = __builtin_amdgcn_mfma_f32_16x16x32_bf16(fA[4], b4, acc, 0, 0, 0);
        acc = __builtin_amdgcn_mfma_f32_16x16x32_bf16(fA[5], b5, acc, 0, 0, 0);

        #pragma unroll
        for (int r = 0; r < 4; ++r)
            out_f[(size_t)(nBase + wv * 16 + (q << 2) + r) * M
                  + mBase + (mt << 4) + l] = acc[r];
    }
}

// ===========================================================================
// dft_fused (no-ws fallback only — validated R5-R9, unchanged).
// ===========================================================================
__global__ __launch_bounds__(256) void dft_fused(const float* __restrict__ H,
                                                 float* __restrict__ HfR,
                                                 float* __restrict__ HfI) {
    __shared__ float  sh[M];
    __shared__ float2 sG[64 * 65];
    const int d = blockIdx.y, tid = threadIdx.x;
    for (int k = tid; k < M; k += 256) sh[k] = softplus_f(H[d * M + k]);
    __syncthreads();

    const int k0 = tid & 63;
    const int rB = (tid >> 6) * 16;
    float twR[16], twI[16], stR[16], stI[16], aR[16], aI[16];
    #pragma unroll
    for (int rr = 0; rr < 16; ++rr) {
        const float ang = (-2.0f * (float)M_PI / 64.0f) * (float)(rB + rr);
        __sincosf(ang, &stI[rr], &stR[rr]);
        twR[rr] = 1.f; twI[rr] = 0.f; aR[rr] = 0.f; aI[rr] = 0.f;
    }
    for (int k1 = 0; k1 < 64; ++k1) {
        const float h = sh[(k1 << 6) + k0];
        #pragma unroll
        for (int rr = 0; rr < 16; ++rr) {
            aR[rr] = fmaf(h, twR[rr], aR[rr]);
            aI[rr] = fmaf(h, twI[rr], aI[rr]);
            const float nR = fmaf(twR[rr], stR[rr], -twI[rr] * stI[rr]);
            const float nI = fmaf(twR[rr], stI[rr],  twI[rr] * stR[rr]);
            twR[rr] = nR; twI[rr] = nI;
        }
    }
    #pragma unroll
    for (int rr = 0; rr < 16; ++rr)
        sG[k0 * 65 + rB + rr] = make_float2(aR[rr], aI[rr]);
    __syncthreads();

    const int mBase = blockIdx.x * 1024;
    for (int j = 0; j < 4; ++j) {
        const int m = mBase + j * 256 + tid;
        const int r = m & 63;
        float ss, sc; __sincosf(PHI1 * (float)m, &ss, &sc);
        float tR_ = 1.f, tI_ = 0.f, accR = 0.f, accI = 0.f;
        #pragma unroll 8
        for (int qq = 0; qq < 64; ++qq) {
            const float2 g = sG[qq * 65 + r];
            accR = fmaf(tR_, g.x, fmaf(-tI_, g.y, accR));
            accI = fmaf(tR_, g.y, fmaf( tI_, g.x, accI));
            const float nR = fmaf(tR_, sc, -tI_ * ss);
            const float nI = fmaf(tR_, ss,  tI_ * sc);
            tR_ = nR; tI_ = nI;
        }
        HfR[d * M + m] = accR;
        HfI[d * M + m] = accI;
    }
}

// ===========================================================================
// VALU einsum v8 (validated R13) — kept for cplx / fallback paths (unchanged).
// ===========================================================================
template <bool CPLX, int U>
__global__ __launch_bounds__(256) void einsum_kernel(const float* __restrict__ W,
                                                     const float* __restrict__ tau,
                                                     const float* __restrict__ HfR,
                                                     const float* __restrict__ HfI,
                                                     float* __restrict__ out_f) {
    constexpr int ROWS = 16 * U;
    constexpr int MT   = 128;
    __shared__ float2 sHf[16 * MT];
    __shared__ float  sW[ROWS][RANK], sT[ROWS][RANK];
    const int tid   = threadIdx.x;
    const int mBase = blockIdx.x * MT;
    const int nBase = blockIdx.y * ROWS;

    for (int i = tid; i < ROWS * RANK; i += 256) {
        const int n_ = i >> 5, dd = i & 31;
        sW[n_][dd] = softplus_f(W[(nBase + n_) * RANK + dd]);
        sT[n_][dd] = tau[(nBase + n_) * RANK + dd];
    }

    const int nl = tid >> 4, chunk = tid & 15;
    const int m0 = mBase + (chunk << 3);

    float accR[U][8], accI[U][8];
    #pragma unroll
    for (int u = 0; u < U; ++u)
        #pragma unroll
        for (int j = 0; j < 8; ++j) { accR[u][j] = 0.f; if (CPLX) accI[u][j] = 0.f; }

    for (int half = 0; half < 2; ++half) {
        __syncthreads();
        for (int e = tid; e < 16 * 64; e += 256) {
            const int dl = e >> 6, p = e & 63;
            const int mm = p << 1;
            const int base = (half * 16 + dl) * M + mBase + mm;
            const float2 r2 = *(const float2*)(HfR + base);
            const float2 q2 = *(const float2*)(HfI + base);
            const int c = mm >> 3, j0 = mm & 7;
            float2* s2 = sHf + (dl << 7);
            s2[(j0 << 4) + c]       = make_float2(r2.x, q2.x);
            s2[((j0 + 1) << 4) + c] = make_float2(r2.y, q2.y);
        }
        __syncthreads();

        #pragma unroll 1
        for (int dl = 0; dl < 16; ++dl) {
            const int dd = (half << 4) + dl;
            float aR_[U], aI_[U], bR_[U], bI_[U], K[U];
            #pragma unroll
            for (int u = 0; u < U; ++u) {
                const float t = sT[nl * U + u][dd], w = sW[nl * U + u][dd];
                const float a1 = PHI1 * t;
                float sp, cp; __sincosf(a1, &sp, &cp);
                float s0, c0; __sincosf(a1 * (float)m0, &s0, &c0);
                aR_[u] = w * c0;
                aI_[u] = w * s0;
                bR_[u] = fmaf(aR_[u], cp, -aI_[u] * sp);
                bI_[u] = fmaf(aI_[u], cp,  aR_[u] * sp);
                K[u]   = 2.0f * cp;
            }
            int idx = (dl << 7) + chunk;
            #pragma unroll
            for (int j = 0; j < 8; ++j) {
                const float2 h = sHf[idx];
                #pragma unroll
                for (int u = 0; u < U; ++u) {
                    accR[u][j] = fmaf(aR_[u], h.x, fmaf(-aI_[u], h.y, accR[u][j]));
                    if (CPLX) accI[u][j] = fmaf(aR_[u], h.y, fmaf(aI_[u], h.x, accI[u][j]));
                    const float nR = fmaf(K[u], bR_[u], -aR_[u]);
                    const float nI = fmaf(K[u], bI_[u], -aI_[u]);
                    aR_[u] = bR_[u]; aI_[u] = bI_[u];
                    bR_[u] = nR;     bI_[u] = nI;
                }
                idx += 16;
            }
        }
    }

    #pragma unroll
    for (int u = 0; u < U; ++u) {
        const int n = nBase + nl * U + u;
        if (CPLX) {
            float2* o2 = ((float2*)out_f) + (size_t)n * M + m0;
            #pragma unroll
            for (int qq = 0; qq < 4; ++qq)
                ((float4*)o2)[qq] = make_float4(accR[u][2*qq], accI[u][2*qq],
                                                accR[u][2*qq+1], accI[u][2*qq+1]);
        } else {
            float* op = out_f + (size_t)n * M + m0;
            ((float4*)op)[0] = make_float4(accR[u][0], accR[u][1], accR[u][2], accR[u][3]);
            ((float4*)op)[1] = make_float4(accR[u][4], accR[u][5], accR[u][6], accR[u][7]);
        }
    }
}

// ===========================================================================
// Tail kernels (no-ws fallback only — dead given 268 MB ws, unchanged).
// ===========================================================================
__global__ __launch_bounds__(256) void tail_real(const float* __restrict__ W,
                                                 const float* __restrict__ tau,
                                                 const float* __restrict__ stashR,
                                                 const float* __restrict__ stashI,
                                                 float* __restrict__ out_f) {
    __shared__ float stR[32 * 32], stI[32 * 32];
    __shared__ float sW[64][RANK], sT[64][RANK];
    const int tid = threadIdx.x;
    const int c0  = blockIdx.x * 32;
    const int nBase = N - 64;
    for (int i = tid; i < 64 * RANK; i += 256) {
        const int n_ = i >> 5, dd = i & 31;
        sW[n_][dd] = softplus_f(W[(nBase + n_) * RANK + dd]);
        sT[n_][dd] = tau[(nBase + n_) * RANK + dd];
    }
    for (int i = tid; i < 32 * 32; i += 256) {
        const int d_ = i >> 5, mm = i & 31;
        stR[i] = stashR[d_ * M + c0 + mm];
        stI[i] = stashI[d_ * M + c0 + mm];
    }
    __syncthreads();
    const int n = tid >> 2, chunk = tid & 3;
    const int m0 = c0 + chunk;
    float acc[8];
    #pragma unroll
    for (int j = 0; j < 8; ++j) acc[j] = 0.f;
    for (int d = 0; d < RANK; ++d) {
        const float t = sT[n][d], w = sW[n][d];
        const float a1 = PHI1 * t;
        float ss, sc; __sincosf(a1 * 4.0f, &ss, &sc);
        float s0, c0f; __sincosf(a1 * (float)m0, &s0, &c0f);
        float tR_ = w * c0f, tI_ = w * s0;
        int idx = (d << 5) + chunk;
        #pragma unroll
        for (int j = 0; j < 8; ++j) {
            acc[j] = fmaf(tR_, stR[idx], fmaf(-tI_, stI[idx], acc[j]));
            const float nR = fmaf(tR_, sc, -tI_ * ss);
            const float nI = fmaf(tR_, ss,  tI_ * sc);
            tR_ = nR; tI_ = nI;
            idx += 4;
        }
    }
    #pragma unroll
    for (int j = 0; j < 8; ++j)
        out_f[(size_t)(nBase + n) * M + m0 + (j << 2)] = acc[j];
}

__global__ __launch_bounds__(256) void tail_cplx(const float* __restrict__ W,
                                                 const float* __restrict__ tau,
                                                 const float* __restrict__ stashR,
                                                 const float* __restrict__ stashI,
                                                 float* __restrict__ out_f) {
    const int nBase = N - 32;
    __shared__ float sW[32][RANK], sT[32][RANK];
    const int tid = threadIdx.x, mBase = blockIdx.x * 256;
    for (int i = tid; i < 32 * RANK; i += 256) {
        const int n_ = i >> 5, dd = i & 31;
        sW[n_][dd] = softplus_f(W[(nBase + n_) * RANK + dd]);
        sT[n_][dd] = tau[(nBase + n_) * RANK + dd];
    }
    const int m = mBase + tid;
    float hr[RANK], hi[RANK];
    #pragma unroll
    for (int d = 0; d < RANK; ++d) { hr[d] = stashR[d * M + m]; hi[d] = stashI[d * M + m]; }
    __syncthreads();
    const float phi = PHI1 * (float)m;
    for (int n_ = 0; n_ < 32; ++n_) {
        float aR = 0.f, aI = 0.f;
        #pragma unroll
        for (int d = 0; d < RANK; ++d) {
            const float t = sT[n_][d], w = sW[n_][d];
            float s, c; __sincosf(t * phi, &s, &c);
            const float cw = c * w, sw = s * w;
            aR = fmaf(cw, hr[d], fmaf(-sw, hi[d], aR));
            aI = fmaf(cw, hi[d], fmaf( sw, hr[d], aI));
        }
        ((float2*)out_f)[(size_t)(nBase + n_) * M + m] = make_float2(aR, aI);
    }
}

// ---------------------------------------------------------------------------
extern "C" void kernel_launch(void* const* d_in, const int* in_sizes, int n_in,
                              void* d_out, int out_size, void* d_ws, size_t ws_size,
                              hipStream_t stream) {
    const float* W   = (const float*)d_in[0];
    const float* H   = (const float*)d_in[1];
    const float* tau = (const float*)d_in[2];
    float* out_f = (float*)d_out;

    const bool   cplx   = (out_size >= 2 * N * M);
    const size_t planeN = (size_t)RANK * M;            // 131072 floats / plane

    static int coop_ok = -1;   // -1 unknown, 1 works, 0 rejected (per-process)

    if (d_ws != nullptr && ws_size >= 4 * planeN * sizeof(float)) {
        float* HfR = (float*)d_ws;
        float* HfI = HfR + planeN;
        float* GR  = HfI + planeN;
        float* GI  = GR  + planeN;

        if (!cplx) {
            if (coop_ok != 0) {
                void* args[8] = {(void*)&W, (void*)&tau, (void*)&H,
                                 (void*)&GR, (void*)&GI,
                                 (void*)&HfR, (void*)&HfI, (void*)&out_f};
                const hipError_t e = hipLaunchCooperativeKernel(
                    reinterpret_cast<const void*>(mega_real),
                    dim3(1024), dim3(256), args, 0u, stream);
                if (e == hipSuccess) { coop_ok = 1; return; }
                coop_ok = 0;
                (void)hipGetLastError();   // clear sticky error, fall through
            }
            // Fallback: proven R19 3-kernel path.
            dft_s1<<<dim3(8, 32), 256, 0, stream>>>(H, GR, GI);
            dft_s2<<<dim3(16, 32), 256, 0, stream>>>(GR, GI, HfR, HfI);
            einsum_mfma<<<dim3(64, 16), 256, 0, stream>>>(W, tau, HfR, HfI, out_f);
        } else {
            dft_s1<<<dim3(8, 32), 256, 0, stream>>>(H, GR, GI);
            dft_s2<<<dim3(16, 32), 256, 0, stream>>>(GR, GI, HfR, HfI);
            einsum_kernel<true , 2><<<dim3(32, N / 32), 256, 0, stream>>>(W, tau, HfR, HfI, out_f);
        }
    } else if (!cplx) {
        float* HfR = out_f + (size_t)(N - 64) * M;     // stash in last 64 real rows
        float* HfI = HfR + planeN;
        dft_fused<<<dim3(4, 32), 256, 0, stream>>>(H, HfR, HfI);
        einsum_kernel<false, 2><<<dim3(32, (N - 64) / 32), 256, 0, stream>>>(W, tau, HfR, HfI, out_f);
        tail_real<<<dim3(128), 256, 0, stream>>>(W, tau, HfR, HfI, out_f);
    } else {
        float* HfR = out_f + 2 * (size_t)N * M - 2 * planeN;  // last 32 cplx rows
        float* HfI = HfR + planeN;
        dft_fused<<<dim3(4, 32), 256, 0, stream>>>(H, HfR, HfI);
        einsum_kernel<true , 2><<<dim3(32, (N - 32) / 32), 256, 0, stream>>>(W, tau, HfR, HfI, out_f);
        tail_cplx<<<dim3(16), 256, 0, stream>>>(W, tau, HfR, HfI, out_f);
    }
}

// Round 5
// 78.344 us; speedup vs baseline: 1.1744x; 1.0413x over previous
//
#include <hip/hip_runtime.h>
#include <hip/hip_bf16.h>
#include <math.h>

#ifndef M_PI
#define M_PI 3.14159265358979323846
#endif

constexpr int N    = 1024;
constexpr int M    = 4096;
constexpr int RANK = 32;
constexpr float PHI1 = -1.5339807878856412e-3f;   // -2*pi/4096

typedef __attribute__((ext_vector_type(8))) short bf16x8;
typedef __attribute__((ext_vector_type(4))) float f32x4;

// Branch-free fast softplus: max(x,0) + log(1+e^-|x|); HW exp/log, err ~1e-7.
__device__ __forceinline__ float softplus_f(float x) {
    const float t = __expf(-fabsf(x));
    return fmaxf(x, 0.0f) + __logf(1.0f + t);
}

// HW RNE bf16 pair-convert (compiler forms v_cvt_pk_bf16_f32 from scalar casts).
__device__ __forceinline__ unsigned pack_bf16x2(float a, float b) {
    __hip_bfloat162 p;
    p.x = __float2bfloat16(a);
    p.y = __float2bfloat16(b);
    unsigned r;
    __builtin_memcpy(&r, &p, 4);
    return r;
}

// ---------------------------------------------------------------------------
// A-side Taylor terms for one (n,d): o = {R0, -I0, R1, -I1, R2, -I2}.
// ---------------------------------------------------------------------------
__device__ __forceinline__ void a_terms(float w, float t, float mcF, float* o) {
    const float sw = softplus_f(w);
    const float a1 = PHI1 * t;
    float s0, c0; __sincosf(a1 * mcF, &s0, &c0);
    const float R0 = sw * c0,  I0 = sw * s0;
    const float R1 = -a1 * I0, I1 = a1 * R0;
    const float h  = 0.5f * a1;
    const float R2 = -h * I1,  I2 = h * R1;
    o[0] = R0; o[1] = -I0; o[2] = R1; o[3] = -I1; o[4] = R2; o[5] = -I2;
}

// ===========================================================================
// R21 fused DFT (dft_bal): stage1 + stage2 in ONE kernel via mod-8 split.
// Block (c,d), c=0..7, d=0..31 (grid 8x32 = 256 = 1/CU):
//   stage 1: rows r = c + 8*rr (rr=0..7) -> sG[8][65] float2 in LDS (4.2 KB).
//   stage 2: m with m % 8 == c; needed row r = m&63 = c + 8*((m>>3)&7) is
//            exactly one of this block's 8 rows.  One __syncthreads replaces
//            a kernel boundary (R20 showed grid.sync costs ~150us/barrier —
//            conventional fusion instead).  Math op-for-op identical to the
//            validated s1/s2 (same recurrences/init) -> Hf bit-identical.
// LDS 20.5 KB.  G never round-trips HBM.
// ===========================================================================
__global__ __launch_bounds__(256) void dft_bal(const float* __restrict__ H,
                                               float* __restrict__ HfR,
                                               float* __restrict__ HfI) {
    __shared__ float  sh[M];          // 16 KB softplus'd row
    __shared__ float2 sG[8 * 65];     // 4.16 KB  [rr][k0], stride 65
    const int c   = blockIdx.x;       // 0..7
    const int d   = blockIdx.y;       // 0..31
    const int tid = threadIdx.x;

    const float4* H4 = (const float4*)(H + d * M);
    for (int i = tid; i < M / 4; i += 256) {
        const float4 v = H4[i];
        ((float4*)sh)[i] = make_float4(softplus_f(v.x), softplus_f(v.y),
                                       softplus_f(v.z), softplus_f(v.w));
    }
    __syncthreads();

    // ---- stage 1: G[r][k0] = sum_k1 sh[64*k1+k0] e^{-2pi i k1 r/64},
    //      r = c + 8*rr.  thread = (k0, rgrp); 2 rr per thread.
    {
        const int k0   = tid & 63;
        const int rgrp = tid >> 6;            // 0..3
        const int rr0  = rgrp * 2;
        const int r0   = c + 8 * rr0;
        const int r1   = r0 + 8;
        float s0, c0, s1, c1;
        __sincosf((-2.0f * (float)M_PI / 64.0f) * (float)r0, &s0, &c0);
        __sincosf((-2.0f * (float)M_PI / 64.0f) * (float)r1, &s1, &c1);
        float twR0 = 1.f, twI0 = 0.f, aR0 = 0.f, aI0 = 0.f;
        float twR1 = 1.f, twI1 = 0.f, aR1 = 0.f, aI1 = 0.f;
        for (int k1 = 0; k1 < 64; ++k1) {
            const float h = sh[(k1 << 6) + k0];
            aR0 = fmaf(h, twR0, aR0);  aI0 = fmaf(h, twI0, aI0);
            aR1 = fmaf(h, twR1, aR1);  aI1 = fmaf(h, twI1, aI1);
            float nR = fmaf(twR0, c0, -twI0 * s0);
            float nI = fmaf(twR0, s0,  twI0 * c0);
            twR0 = nR; twI0 = nI;
            nR = fmaf(twR1, c1, -twI1 * s1);
            nI = fmaf(twR1, s1,  twI1 * c1);
            twR1 = nR; twI1 = nI;
        }
        sG[rr0 * 65 + k0]       = make_float2(aR0, aI0);
        sG[(rr0 + 1) * 65 + k0] = make_float2(aR1, aI1);
    }
    __syncthreads();

    // ---- stage 2: Hf[d][m] = sum_k0 G[m&63][k0] e^{i PHI1 k0 m},
    //      m = c + 8*(tid + 256*j).  rr = tid&7 for both j (256 % 8 == 0).
    const int rr = tid & 7;
    #pragma unroll
    for (int j = 0; j < 2; ++j) {
        const int m = c + 8 * (tid + 256 * j);
        float ss, sc; __sincosf(PHI1 * (float)m, &ss, &sc);
        float tR_ = 1.f, tI_ = 0.f, accR = 0.f, accI = 0.f;
        #pragma unroll 8
        for (int k0 = 0; k0 < 64; ++k0) {
            const float2 g = sG[rr * 65 + k0];
            accR = fmaf(tR_, g.x, fmaf(-tI_, g.y, accR));
            accI = fmaf(tR_, g.y, fmaf( tI_, g.x, accI));
            const float nR = fmaf(tR_, sc, -tI_ * ss);
            const float nI = fmaf(tR_, ss,  tI_ * sc);
            tR_ = nR; tI_ = nI;
        }
        HfR[d * M + m] = accR;
        HfI[d * M + m] = accI;
    }
}

// ===========================================================================
// MFMA einsum (R19, validated 82.1 us) — unchanged.
// ===========================================================================
__global__ __launch_bounds__(256, 4) void einsum_mfma(const float* __restrict__ W,
                                                      const float* __restrict__ tau,
                                                      const float* __restrict__ HfR,
                                                      const float* __restrict__ HfI,
                                                      float* __restrict__ out_f) {
    __shared__ __attribute__((aligned(16))) unsigned short sB[6][64][40]; // 30720 B
    const int tid   = threadIdx.x;
    const int mBase = blockIdx.x * 64;
    const int nBase = blockIdx.y * 64;

    const int wv = tid >> 6, lane = tid & 63;
    const int q = lane >> 4, l = lane & 15;
    const int nA = nBase + wv * 16 + l;
    const int d8 = q << 3;
    const float mcF = (float)(mBase + 32);

    const float4 w0 = *(const float4*)(W   + nA * RANK + d8);
    const float4 w1 = *(const float4*)(W   + nA * RANK + d8 + 4);
    const float4 t0 = *(const float4*)(tau + nA * RANK + d8);
    const float4 t1 = *(const float4*)(tau + nA * RANK + d8 + 4);

    for (int e = tid; e < 512; e += 256) {
        const int mloc = e & 63;
        const int d0   = (e >> 6) << 2;
        const float dlt = (float)mloc - 32.0f;
        const float dq  = dlt * dlt;
        const float* pR = HfR + d0 * M + mBase + mloc;
        const float* pI = HfI + d0 * M + mBase + mloc;
        float r0 = pR[0], r1 = pR[M], r2 = pR[2*M], r3 = pR[3*M];
        float i0 = pI[0], i1 = pI[M], i2 = pI[2*M], i3 = pI[3*M];

        uint2 v;
        v.x = pack_bf16x2(r0, r1);           v.y = pack_bf16x2(r2, r3);
        *(uint2*)&sB[0][mloc][d0] = v;
        v.x = pack_bf16x2(i0, i1);           v.y = pack_bf16x2(i2, i3);
        *(uint2*)&sB[1][mloc][d0] = v;
        v.x = pack_bf16x2(r0*dlt, r1*dlt);   v.y = pack_bf16x2(r2*dlt, r3*dlt);
        *(uint2*)&sB[2][mloc][d0] = v;
        v.x = pack_bf16x2(i0*dlt, i1*dlt);   v.y = pack_bf16x2(i2*dlt, i3*dlt);
        *(uint2*)&sB[3][mloc][d0] = v;
        v.x = pack_bf16x2(r0*dq, r1*dq);     v.y = pack_bf16x2(r2*dq, r3*dq);
        *(uint2*)&sB[4][mloc][d0] = v;
        v.x = pack_bf16x2(i0*dq, i1*dq);     v.y = pack_bf16x2(i2*dq, i3*dq);
        *(uint2*)&sB[5][mloc][d0] = v;
    }

    const float wj[8] = {w0.x,w0.y,w0.z,w0.w,w1.x,w1.y,w1.z,w1.w};
    const float tj[8] = {t0.x,t0.y,t0.z,t0.w,t1.x,t1.y,t1.z,t1.w};
    unsigned uA[6][4];
    #pragma unroll
    for (int p = 0; p < 4; ++p) {
        float f0[6], f1[6];
        a_terms(wj[2*p],   tj[2*p],   mcF, f0);
        a_terms(wj[2*p+1], tj[2*p+1], mcF, f1);
        #pragma unroll
        for (int k = 0; k < 6; ++k) uA[k][p] = pack_bf16x2(f0[k], f1[k]);
    }
    bf16x8 fA[6];
    #pragma unroll
    for (int k = 0; k < 6; ++k) __builtin_memcpy(&fA[k], uA[k], 16);
    __syncthreads();

    for (int mt = 0; mt < 4; ++mt) {
        const int mL = (mt << 4) + l;
        const bf16x8 b0 = *(const bf16x8*)&sB[0][mL][d8];
        const bf16x8 b1 = *(const bf16x8*)&sB[1][mL][d8];
        const bf16x8 b2 = *(const bf16x8*)&sB[2][mL][d8];
        const bf16x8 b3 = *(const bf16x8*)&sB[3][mL][d8];
        const bf16x8 b4 = *(const bf16x8*)&sB[4][mL][d8];
        const bf16x8 b5 = *(const bf16x8*)&sB[5][mL][d8];

        f32x4 acc = {0.f, 0.f, 0.f, 0.f};
        acc = __builtin_amdgcn_mfma_f32_16x16x32_bf16(fA[0], b0, acc, 0, 0, 0);
        acc = __builtin_amdgcn_mfma_f32_16x16x32_bf16(fA[1], b1, acc, 0, 0, 0);
        acc = __builtin_amdgcn_mfma_f32_16x16x32_bf16(fA[2], b2, acc, 0, 0, 0);
        acc = __builtin_amdgcn_mfma_f32_16x16x32_bf16(fA[3], b3, acc, 0, 0, 0);
        acc = __builtin_amdgcn_mfma_f32_16x16x32_bf16(fA[4], b4, acc, 0, 0, 0);
        acc = __builtin_amdgcn_mfma_f32_16x16x32_bf16(fA[5], b5, acc, 0, 0, 0);

        #pragma unroll
        for (int r = 0; r < 4; ++r)
            out_f[(size_t)(nBase + wv * 16 + (q << 2) + r) * M
                  + mBase + (mt << 4) + l] = acc[r];
    }
}

// ===========================================================================
// dft_fused (no-ws fallback only — validated R5-R9, unchanged).
// ===========================================================================
__global__ __launch_bounds__(256) void dft_fused(const float* __restrict__ H,
                                                 float* __restrict__ HfR,
                                                 float* __restrict__ HfI) {
    __shared__ float  sh[M];
    __shared__ float2 sG[64 * 65];
    const int d = blockIdx.y, tid = threadIdx.x;
    for (int k = tid; k < M; k += 256) sh[k] = softplus_f(H[d * M + k]);
    __syncthreads();

    const int k0 = tid & 63;
    const int rB = (tid >> 6) * 16;
    float twR[16], twI[16], stR[16], stI[16], aR[16], aI[16];
    #pragma unroll
    for (int rr = 0; rr < 16; ++rr) {
        const float ang = (-2.0f * (float)M_PI / 64.0f) * (float)(rB + rr);
        __sincosf(ang, &stI[rr], &stR[rr]);
        twR[rr] = 1.f; twI[rr] = 0.f; aR[rr] = 0.f; aI[rr] = 0.f;
    }
    for (int k1 = 0; k1 < 64; ++k1) {
        const float h = sh[(k1 << 6) + k0];
        #pragma unroll
        for (int rr = 0; rr < 16; ++rr) {
            aR[rr] = fmaf(h, twR[rr], aR[rr]);
            aI[rr] = fmaf(h, twI[rr], aI[rr]);
            const float nR = fmaf(twR[rr], stR[rr], -twI[rr] * stI[rr]);
            const float nI = fmaf(twR[rr], stI[rr],  twI[rr] * stR[rr]);
            twR[rr] = nR; twI[rr] = nI;
        }
    }
    #pragma unroll
    for (int rr = 0; rr < 16; ++rr)
        sG[k0 * 65 + rB + rr] = make_float2(aR[rr], aI[rr]);
    __syncthreads();

    const int mBase = blockIdx.x * 1024;
    for (int j = 0; j < 4; ++j) {
        const int m = mBase + j * 256 + tid;
        const int r = m & 63;
        float ss, sc; __sincosf(PHI1 * (float)m, &ss, &sc);
        float tR_ = 1.f, tI_ = 0.f, accR = 0.f, accI = 0.f;
        #pragma unroll 8
        for (int qq = 0; qq < 64; ++qq) {
            const float2 g = sG[qq * 65 + r];
            accR = fmaf(tR_, g.x, fmaf(-tI_, g.y, accR));
            accI = fmaf(tR_, g.y, fmaf( tI_, g.x, accI));
            const float nR = fmaf(tR_, sc, -tI_ * ss);
            const float nI = fmaf(tR_, ss,  tI_ * sc);
            tR_ = nR; tI_ = nI;
        }
        HfR[d * M + m] = accR;
        HfI[d * M + m] = accI;
    }
}

// ===========================================================================
// VALU einsum v8 (validated R13) — kept for cplx / fallback paths (unchanged).
// ===========================================================================
template <bool CPLX, int U>
__global__ __launch_bounds__(256) void einsum_kernel(const float* __restrict__ W,
                                                     const float* __restrict__ tau,
                                                     const float* __restrict__ HfR,
                                                     const float* __restrict__ HfI,
                                                     float* __restrict__ out_f) {
    constexpr int ROWS = 16 * U;
    constexpr int MT   = 128;
    __shared__ float2 sHf[16 * MT];
    __shared__ float  sW[ROWS][RANK], sT[ROWS][RANK];
    const int tid   = threadIdx.x;
    const int mBase = blockIdx.x * MT;
    const int nBase = blockIdx.y * ROWS;

    for (int i = tid; i < ROWS * RANK; i += 256) {
        const int n_ = i >> 5, dd = i & 31;
        sW[n_][dd] = softplus_f(W[(nBase + n_) * RANK + dd]);
        sT[n_][dd] = tau[(nBase + n_) * RANK + dd];
    }

    const int nl = tid >> 4, chunk = tid & 15;
    const int m0 = mBase + (chunk << 3);

    float accR[U][8], accI[U][8];
    #pragma unroll
    for (int u = 0; u < U; ++u)
        #pragma unroll
        for (int j = 0; j < 8; ++j) { accR[u][j] = 0.f; if (CPLX) accI[u][j] = 0.f; }

    for (int half = 0; half < 2; ++half) {
        __syncthreads();
        for (int e = tid; e < 16 * 64; e += 256) {
            const int dl = e >> 6, p = e & 63;
            const int mm = p << 1;
            const int base = (half * 16 + dl) * M + mBase + mm;
            const float2 r2 = *(const float2*)(HfR + base);
            const float2 q2 = *(const float2*)(HfI + base);
            const int c = mm >> 3, j0 = mm & 7;
            float2* s2 = sHf + (dl << 7);
            s2[(j0 << 4) + c]       = make_float2(r2.x, q2.x);
            s2[((j0 + 1) << 4) + c] = make_float2(r2.y, q2.y);
        }
        __syncthreads();

        #pragma unroll 1
        for (int dl = 0; dl < 16; ++dl) {
            const int dd = (half << 4) + dl;
            float aR_[U], aI_[U], bR_[U], bI_[U], K[U];
            #pragma unroll
            for (int u = 0; u < U; ++u) {
                const float t = sT[nl * U + u][dd], w = sW[nl * U + u][dd];
                const float a1 = PHI1 * t;
                float sp, cp; __sincosf(a1, &sp, &cp);
                float s0, c0; __sincosf(a1 * (float)m0, &s0, &c0);
                aR_[u] = w * c0;
                aI_[u] = w * s0;
                bR_[u] = fmaf(aR_[u], cp, -aI_[u] * sp);
                bI_[u] = fmaf(aI_[u], cp,  aR_[u] * sp);
                K[u]   = 2.0f * cp;
            }
            int idx = (dl << 7) + chunk;
            #pragma unroll
            for (int j = 0; j < 8; ++j) {
                const float2 h = sHf[idx];
                #pragma unroll
                for (int u = 0; u < U; ++u) {
                    accR[u][j] = fmaf(aR_[u], h.x, fmaf(-aI_[u], h.y, accR[u][j]));
                    if (CPLX) accI[u][j] = fmaf(aR_[u], h.y, fmaf(aI_[u], h.x, accI[u][j]));
                    const float nR = fmaf(K[u], bR_[u], -aR_[u]);
                    const float nI = fmaf(K[u], bI_[u], -aI_[u]);
                    aR_[u] = bR_[u]; aI_[u] = bI_[u];
                    bR_[u] = nR;     bI_[u] = nI;
                }
                idx += 16;
            }
        }
    }

    #pragma unroll
    for (int u = 0; u < U; ++u) {
        const int n = nBase + nl * U + u;
        if (CPLX) {
            float2* o2 = ((float2*)out_f) + (size_t)n * M + m0;
            #pragma unroll
            for (int qq = 0; qq < 4; ++qq)
                ((float4*)o2)[qq] = make_float4(accR[u][2*qq], accI[u][2*qq],
                                                accR[u][2*qq+1], accI[u][2*qq+1]);
        } else {
            float* op = out_f + (size_t)n * M + m0;
            ((float4*)op)[0] = make_float4(accR[u][0], accR[u][1], accR[u][2], accR[u][3]);
            ((float4*)op)[1] = make_float4(accR[u][4], accR[u][5], accR[u][6], accR[u][7]);
        }
    }
}

// ===========================================================================
// Tail kernels (no-ws fallback only — dead given 268 MB ws, unchanged).
// ===========================================================================
__global__ __launch_bounds__(256) void tail_real(const float* __restrict__ W,
                                                 const float* __restrict__ tau,
                                                 const float* __restrict__ stashR,
                                                 const float* __restrict__ stashI,
                                                 float* __restrict__ out_f) {
    __shared__ float stR[32 * 32], stI[32 * 32];
    __shared__ float sW[64][RANK], sT[64][RANK];
    const int tid = threadIdx.x;
    const int c0  = blockIdx.x * 32;
    const int nBase = N - 64;
    for (int i = tid; i < 64 * RANK; i += 256) {
        const int n_ = i >> 5, dd = i & 31;
        sW[n_][dd] = softplus_f(W[(nBase + n_) * RANK + dd]);
        sT[n_][dd] = tau[(nBase + n_) * RANK + dd];
    }
    for (int i = tid; i < 32 * 32; i += 256) {
        const int d_ = i >> 5, mm = i & 31;
        stR[i] = stashR[d_ * M + c0 + mm];
        stI[i] = stashI[d_ * M + c0 + mm];
    }
    __syncthreads();
    const int n = tid >> 2, chunk = tid & 3;
    const int m0 = c0 + chunk;
    float acc[8];
    #pragma unroll
    for (int j = 0; j < 8; ++j) acc[j] = 0.f;
    for (int d = 0; d < RANK; ++d) {
        const float t = sT[n][d], w = sW[n][d];
        const float a1 = PHI1 * t;
        float ss, sc; __sincosf(a1 * 4.0f, &ss, &sc);
        float s0, c0f; __sincosf(a1 * (float)m0, &s0, &c0f);
        float tR_ = w * c0f, tI_ = w * s0;
        int idx = (d << 5) + chunk;
        #pragma unroll
        for (int j = 0; j < 8; ++j) {
            acc[j] = fmaf(tR_, stR[idx], fmaf(-tI_, stI[idx], acc[j]));
            const float nR = fmaf(tR_, sc, -tI_ * ss);
            const float nI = fmaf(tR_, ss,  tI_ * sc);
            tR_ = nR; tI_ = nI;
            idx += 4;
        }
    }
    #pragma unroll
    for (int j = 0; j < 8; ++j)
        out_f[(size_t)(nBase + n) * M + m0 + (j << 2)] = acc[j];
}

__global__ __launch_bounds__(256) void tail_cplx(const float* __restrict__ W,
                                                 const float* __restrict__ tau,
                                                 const float* __restrict__ stashR,
                                                 const float* __restrict__ stashI,
                                                 float* __restrict__ out_f) {
    const int nBase = N - 32;
    __shared__ float sW[32][RANK], sT[32][RANK];
    const int tid = threadIdx.x, mBase = blockIdx.x * 256;
    for (int i = tid; i < 32 * RANK; i += 256) {
        const int n_ = i >> 5, dd = i & 31;
        sW[n_][dd] = softplus_f(W[(nBase + n_) * RANK + dd]);
        sT[n_][dd] = tau[(nBase + n_) * RANK + dd];
    }
    const int m = mBase + tid;
    float hr[RANK], hi[RANK];
    #pragma unroll
    for (int d = 0; d < RANK; ++d) { hr[d] = stashR[d * M + m]; hi[d] = stashI[d * M + m]; }
    __syncthreads();
    const float phi = PHI1 * (float)m;
    for (int n_ = 0; n_ < 32; ++n_) {
        float aR = 0.f, aI = 0.f;
        #pragma unroll
        for (int d = 0; d < RANK; ++d) {
            const float t = sT[n_][d], w = sW[n_][d];
            float s, c; __sincosf(t * phi, &s, &c);
            const float cw = c * w, sw = s * w;
            aR = fmaf(cw, hr[d], fmaf(-sw, hi[d], aR));
            aI = fmaf(cw, hi[d], fmaf( sw, hr[d], aI));
        }
        ((float2*)out_f)[(size_t)(nBase + n_) * M + m] = make_float2(aR, aI);
    }
}

// ---------------------------------------------------------------------------
extern "C" void kernel_launch(void* const* d_in, const int* in_sizes, int n_in,
                              void* d_out, int out_size, void* d_ws, size_t ws_size,
                              hipStream_t stream) {
    const float* W   = (const float*)d_in[0];
    const float* H   = (const float*)d_in[1];
    const float* tau = (const float*)d_in[2];
    float* out_f = (float*)d_out;

    const bool   cplx   = (out_size >= 2 * N * M);
    const size_t planeN = (size_t)RANK * M;            // 131072 floats / plane

    if (d_ws != nullptr && ws_size >= 4 * planeN * sizeof(float)) {
        float* HfR = (float*)d_ws;
        float* HfI = HfR + planeN;
        // R21: fused DFT (one launch) -> einsum.  2 launches total.
        dft_bal<<<dim3(8, 32), 256, 0, stream>>>(H, HfR, HfI);
        if (cplx)
            einsum_kernel<true , 2><<<dim3(32, N / 32), 256, 0, stream>>>(W, tau, HfR, HfI, out_f);
        else
            einsum_mfma<<<dim3(64, 16), 256, 0, stream>>>(W, tau, HfR, HfI, out_f);
    } else if (!cplx) {
        float* HfR = out_f + (size_t)(N - 64) * M;     // stash in last 64 real rows
        float* HfI = HfR + planeN;
        dft_fused<<<dim3(4, 32), 256, 0, stream>>>(H, HfR, HfI);
        einsum_kernel<false, 2><<<dim3(32, (N - 64) / 32), 256, 0, stream>>>(W, tau, HfR, HfI, out_f);
        tail_real<<<dim3(128), 256, 0, stream>>>(W, tau, HfR, HfI, out_f);
    } else {
        float* HfR = out_f + 2 * (size_t)N * M - 2 * planeN;  // last 32 cplx rows
        float* HfI = HfR + planeN;
        dft_fused<<<dim3(4, 32), 256, 0, stream>>>(H, HfR, HfI);
        einsum_kernel<true , 2><<<dim3(32, (N - 32) / 32), 256, 0, stream>>>(W, tau, HfR, HfI, out_f);
        tail_cplx<<<dim3(16), 256, 0, stream>>>(W, tau, HfR, HfI, out_f);
    }
}